// Round 2
// baseline (608.383 us; speedup 1.0000x reference)
//
#include <hip/hip_runtime.h>
#include <hip/hip_bf16.h>

using bf16 = __hip_bfloat16;

__device__ __forceinline__ float b2f(bf16 x) { return __bfloat162float(x); }
__device__ __forceinline__ bf16  f2b(float x) { return __float2bfloat16(x); }
// flag-dispatched input load: f32==1 -> fp32 storage, else bf16 storage
__device__ __forceinline__ float ldin(const void* p, int i, int f32) {
    return f32 ? ((const float*)p)[i] : b2f(((const bf16*)p)[i]);
}

// problem dims (fixed by setup_inputs)
#define TI 6
#define HI 40
#define WI 40
#define TO 12
#define HO 80
#define WO 80
#define NIN (TI*HI*WI)    // 9600
#define NOUT (TO*HO*WO)   // 76800

// ---------------- workspace layout ----------------
// [0, P_BYTES)                : P bf16 [8][NIN][256]   (corner projections)
// [P_BYTES, +FC1T_BYTES)      : fc1T bf16 [256][256]   (fc1_w transposed)
// float region F (offsets in floats):
#define F_W1F   0                       // [8*64][256] pw1_w(feat cols)*dw1_w, [k*64+c][o]
#define F_B1    (F_W1F + 8*64*256)      // [256] effective bias
#define F_ACO   (F_B1 + 256)            // [6][256] rel-coord coefficients
#define F_SCW   (F_ACO + 6*256)         // [3][64] sc_pw_w*sc_dw_w
#define F_SCB   (F_SCW + 3*64)          // [3] folded sc bias (pad 4)
#define F_SC    (F_SCB + 4)             // [3][NIN] shortcut conv output
#define F_DT    (F_SC + 3*NIN)          // [2][TO] signed d (t axis)
#define F_DH    (F_DT + 2*TO)           // [2][HO]
#define F_DW    (F_DH + 2*HO)           // [2][WO]
#define F_FT    (F_DW + 2*WO)           // [TO] trilinear frac
#define F_FH    (F_FT + TO)             // [HO]
#define F_FW    (F_FH + HO)             // [WO]
#define F_FC1B  (F_FW + WO)             // [256] fc1 bias (fp32 staged)
#define F_FC2W  (F_FC1B + 256)          // [3*256] fc2 weights (fp32 staged)
#define F_FC2B  (F_FC2W + 768)          // [3] fc2 bias (pad 4)
#define F_END   (F_FC2B + 4)
// int region I (offsets in ints), starts right after F region:
#define I_IT    0                       // [2][TO] nearest idx
#define I_IH    (I_IT + 2*TO)           // [2][HO]
#define I_IW    (I_IH + 2*HO)           // [2][WO]
#define I_LT0   (I_IW + 2*WO)           // [TO] trilinear i0
#define I_LT1   (I_LT0 + TO)
#define I_LH0   (I_LT1 + TO)
#define I_LH1   (I_LH0 + HO)
#define I_LW0   (I_LH1 + HO)
#define I_LW1   (I_LW0 + WO)
#define I_FLAG  (I_LW1 + WO)            // [1] 1 = fp32 storage, 0 = bf16 storage
#define I_END   (I_FLAG + 1)

// per-axis tables, replicating reference `near` (eps=1e-6, round-half-even) and `lin_idx`
__device__ __forceinline__ void axis_tables(int i, int n_out, int n_in,
                                            float* dvals, int* ivals,
                                            int* l0, int* l1, float* fr) {
    const float r_out = 1.0f / (float)n_out;
    const float r_in  = 1.0f / (float)n_in;
    const float c = -1.0f + r_out + 2.0f * r_out * (float)i;
    #pragma unroll
    for (int v = 0; v < 2; ++v) {
        const float vv = v ? 1.0f : -1.0f;
        float cc = c + vv * r_in + 1e-6f;
        cc = fminf(fmaxf(cc, -1.0f + 1e-6f), 1.0f - 1e-6f);
        float fx = rintf(((cc + 1.0f) * (float)n_in - 1.0f) * 0.5f);
        fx = fminf(fmaxf(fx, 0.0f), (float)(n_in - 1));
        const int idx = (int)fx;
        const float l = -1.0f + r_in + 2.0f * r_in * (float)idx;
        dvals[v * n_out + i] = (c - l) * (float)n_in;
        ivals[v * n_out + i] = idx;
    }
    float x = fminf(fmaxf(((c + 1.0f) * (float)n_in - 1.0f) * 0.5f, 0.0f), (float)(n_in - 1));
    const float x0 = floorf(x);
    fr[i] = x - x0;
    const int i0 = (int)x0;
    l0[i] = i0;
    l1[i] = min(i0 + 1, n_in - 1);
}

// ---------------- kernel A: dtype detect + weight folding + tables (1 block) ----------------
__global__ __launch_bounds__(256)
void k_prep(const void* __restrict__ feat,
            const void* __restrict__ dw1_w, const void* __restrict__ dw1_b,
            const void* __restrict__ pw1_w, const void* __restrict__ pw1_b,
            const void* __restrict__ fc1_w, const void* __restrict__ fc1_b,
            const void* __restrict__ fc2_w, const void* __restrict__ fc2_b,
            const void* __restrict__ sc_dw_w, const void* __restrict__ sc_dw_b,
            const void* __restrict__ sc_pw_w, const void* __restrict__ sc_pw_b,
            bf16* __restrict__ fc1T, float* __restrict__ F, int* __restrict__ I) {
    const int tid = threadIdx.x;
    __shared__ int sflag;
    if (tid == 0) {
        // storage detection: even halfwords of fp32 data are mantissa junk
        // (~15% have a plausible bf16 exponent); of bf16 data they are real
        // bf16 samples (~100%). bf16-rounded-fp32 gives all-zero low halves.
        const unsigned short* u = (const unsigned short*)feat;
        int cnt = 0;
        for (int i = 0; i < 256; i += 2) {
            const unsigned e = (u[i] >> 7) & 0xFF;
            cnt += (e >= 0x68 && e <= 0x8E) ? 1 : 0;
        }
        sflag = (cnt < 64) ? 1 : 0;
        I[I_FLAG] = sflag;
    }
    __syncthreads();
    const int f32 = sflag;

    const int o = tid;
    const int prow = o * 539;

    // effective bias: pw1_b + sum pw1_w*dw1_b + 2.0*(rel_cell cols 536..538)
    float bacc = ldin(pw1_b, o, f32);
    for (int ch = 0; ch < 539; ++ch)
        bacc += ldin(pw1_w, prow + ch, f32) * ldin(dw1_b, ch, f32);
    #pragma unroll
    for (int ch = 536; ch < 539; ++ch)
        bacc += 2.0f * ldin(pw1_w, prow + ch, f32) * ldin(dw1_w, ch, f32);
    F[F_B1 + o] = bacc;

    // rel-coord coefficients: corner k has channels 3k(dct),3k+1(dch),3k+2(dcw)
    float A[6] = {0.f, 0.f, 0.f, 0.f, 0.f, 0.f};
    #pragma unroll
    for (int k = 0; k < 8; ++k) {
        A[(k >> 2)]           += ldin(pw1_w, prow + 3*k + 0, f32) * ldin(dw1_w, 3*k + 0, f32);
        A[2 + ((k >> 1) & 1)] += ldin(pw1_w, prow + 3*k + 1, f32) * ldin(dw1_w, 3*k + 1, f32);
        A[4 + (k & 1)]        += ldin(pw1_w, prow + 3*k + 2, f32) * ldin(dw1_w, 3*k + 2, f32);
    }
    #pragma unroll
    for (int i = 0; i < 6; ++i) F[F_ACO + i * 256 + o] = A[i];

    // feature-column weights W1f[k*64+c][o]
    for (int cc = 0; cc < 512; ++cc)
        F[F_W1F + cc * 256 + o] = ldin(pw1_w, prow + 24 + cc, f32) * ldin(dw1_w, 24 + cc, f32);

    // fc1 transpose: fc1T[i][j] = fc1_w[j][i]  (bf16 staging)
    for (int i = 0; i < 256; ++i)
        fc1T[i * 256 + o] = f2b(ldin(fc1_w, o * 256 + i, f32));

    // fp32-staged small tensors for k_main
    F[F_FC1B + o] = ldin(fc1_b, o, f32);
    for (int r = o; r < 768; r += 256) F[F_FC2W + r] = ldin(fc2_w, r, f32);
    if (o < 3) F[F_FC2B + o] = ldin(fc2_b, o, f32);

    // shortcut folded weights
    if (tid < 3) {
        const int j = tid;
        float s = ldin(sc_pw_b, j, f32);
        for (int c = 0; c < 64; ++c) {
            const float pw = ldin(sc_pw_w, j * 64 + c, f32);
            F[F_SCW + j * 64 + c] = pw * ldin(sc_dw_w, c, f32);
            s += pw * ldin(sc_dw_b, c, f32);
        }
        F[F_SCB + j] = s;
    }

    // axis tables
    if (tid < TO) axis_tables(tid, TO, TI, F + F_DT, I + I_IT, I + I_LT0, I + I_LT1, F + F_FT);
    if (tid < HO) axis_tables(tid, HO, HI, F + F_DH, I + I_IH, I + I_LH0, I + I_LH1, F + F_FH);
    if (tid < WO) axis_tables(tid, WO, WI, F + F_DW, I + I_IW, I + I_LW0, I + I_LW1, F + F_FW);
}

// ---------------- kernel B: corner projections P + shortcut sc ----------------
__global__ __launch_bounds__(256)
void k_corner(const void* __restrict__ feat, float* __restrict__ F,
              const int* __restrict__ I, bf16* __restrict__ P) {
    const int tid = threadIdx.x;
    const int pos0 = blockIdx.x * 16;
    const int f32 = I[I_FLAG];
    __shared__ float flds[64][16];   // [c][p]

    for (int idx = tid; idx < 1024; idx += 256) {
        const int c = idx >> 4, p = idx & 15;
        flds[c][p] = ldin(feat, c * NIN + pos0 + p, f32);
    }
    __syncthreads();

    const int o = tid;
    for (int k = 0; k < 8; ++k) {
        float acc[16];
        #pragma unroll
        for (int p = 0; p < 16; ++p) acc[p] = 0.f;
        const float* Wk = F + F_W1F + (k << 6) * 256 + o;
        #pragma unroll 8
        for (int c = 0; c < 64; ++c) {
            const float wv = Wk[c * 256];
            #pragma unroll
            for (int p = 0; p < 16; ++p) acc[p] += wv * flds[c][p];
        }
        bf16* Pk = P + ((size_t)(k * NIN + pos0)) * 256 + o;
        #pragma unroll
        for (int p = 0; p < 16; ++p) Pk[(size_t)p * 256] = f2b(acc[p]);
    }

    // shortcut: sc[j][pos] = sum_c feat*scw + scb
    if (tid < 48) {
        const int j = tid >> 4, p = tid & 15;
        float s = F[F_SCB + j];
        for (int c = 0; c < 64; ++c) s += flds[c][p] * F[F_SCW + j * 64 + c];
        F[F_SC + j * NIN + pos0 + p] = s;
    }
}

// ---------------- kernel C: main fused MLP + trilinear shortcut ----------------
__global__ __launch_bounds__(256)
void k_main(const bf16* __restrict__ P, const bf16* __restrict__ fc1T,
            const float* __restrict__ F, const int* __restrict__ I,
            void* __restrict__ outv) {
    const int tid = threadIdx.x;
    const int pos0 = blockIdx.x * 16;              // 16 consecutive w within one (t,h) row
    const int t = pos0 / (HO * WO);
    const int rem = pos0 - t * (HO * WO);
    const int h = rem / WO;
    const int w0 = rem - h * WO;
    const int f32 = I[I_FLAG];

    __shared__ __align__(16) float zs[16 * 256];   // [p][o], reused for gelu(h) after sync
    __shared__ int   sh_ipos[16][8];
    __shared__ float sh_wk[16][8];
    __shared__ float sh_dv[16][6];
    __shared__ float sh_g[3][16];

    // ---- stage 1: per-position scalars (threads 0..15) ----
    if (tid < 16) {
        const int p = tid;
        const int w = w0 + p;
        const int   iTa[2] = { I[I_IT + t], I[I_IT + TO + t] };
        const float dTv[2] = { F[F_DT + t], F[F_DT + TO + t] };
        const int   iHa[2] = { I[I_IH + h], I[I_IH + HO + h] };
        const float dHv[2] = { F[F_DH + h], F[F_DH + HO + h] };
        const int   iWa[2] = { I[I_IW + w], I[I_IW + WO + w] };
        const float dWv[2] = { F[F_DW + w], F[F_DW + WO + w] };
        sh_dv[p][0] = dTv[0]; sh_dv[p][1] = dTv[1];
        sh_dv[p][2] = dHv[0]; sh_dv[p][3] = dHv[1];
        sh_dv[p][4] = dWv[0]; sh_dv[p][5] = dWv[1];
        const float aT[2] = { fabsf(dTv[0]), fabsf(dTv[1]) };
        const float aH[2] = { fabsf(dHv[0]), fabsf(dHv[1]) };
        const float aW[2] = { fabsf(dWv[0]), fabsf(dWv[1]) };
        const float tot = (aT[0] + aT[1]) * (aH[0] + aH[1]) * (aW[0] + aW[1]) + 8e-9f;
        #pragma unroll
        for (int k = 0; k < 8; ++k) {
            const int at = k >> 2, ah = (k >> 1) & 1, aw = k & 1;
            sh_wk[p][k] = (aT[1 - at] * aH[1 - ah] * aW[1 - aw] + 1e-9f) / tot;
            sh_ipos[p][k] = iTa[at] * (HI * WI) + iHa[ah] * WI + iWa[aw];
        }
        // trilinear shortcut g
        const int a0 = I[I_LT0 + t], a1 = I[I_LT1 + t];
        const int bh0 = I[I_LH0 + h], bh1 = I[I_LH1 + h];
        const int c0 = I[I_LW0 + w], c1 = I[I_LW1 + w];
        const float fT = F[F_FT + t], fH = F[F_FH + h], fW = F[F_FW + w];
        #pragma unroll
        for (int jj = 0; jj < 3; ++jj) {
            const float* Sj = F + F_SC + jj * NIN;
            const int i0 = a0 * (HI * WI), i1 = a1 * (HI * WI);
            const float v000 = Sj[i0 + bh0 * WI + c0], v001 = Sj[i0 + bh0 * WI + c1];
            const float v010 = Sj[i0 + bh1 * WI + c0], v011 = Sj[i0 + bh1 * WI + c1];
            const float v100 = Sj[i1 + bh0 * WI + c0], v101 = Sj[i1 + bh0 * WI + c1];
            const float v110 = Sj[i1 + bh1 * WI + c0], v111 = Sj[i1 + bh1 * WI + c1];
            const float u00 = v000 * (1.f - fT) + v100 * fT;
            const float u01 = v001 * (1.f - fT) + v101 * fT;
            const float u10 = v010 * (1.f - fT) + v110 * fT;
            const float u11 = v011 * (1.f - fT) + v111 * fT;
            const float q0 = u00 * (1.f - fH) + u10 * fH;
            const float q1 = u01 * (1.f - fH) + u11 * fH;
            sh_g[jj][p] = q0 * (1.f - fW) + q1 * fW;
        }
    }
    __syncthreads();

    // ---- stage 2: z[p][o] = b1eff + Acoef·dv + sum_k wk * P[k][ipos][o] ----
    {
        const int o = tid;
        const float bz = F[F_B1 + o];
        const float A0 = F[F_ACO + 0 * 256 + o], A1 = F[F_ACO + 1 * 256 + o];
        const float A2 = F[F_ACO + 2 * 256 + o], A3 = F[F_ACO + 3 * 256 + o];
        const float A4 = F[F_ACO + 4 * 256 + o], A5 = F[F_ACO + 5 * 256 + o];
        #pragma unroll
        for (int p = 0; p < 16; ++p) {
            float a = bz + A0 * sh_dv[p][0] + A1 * sh_dv[p][1] + A2 * sh_dv[p][2]
                         + A3 * sh_dv[p][3] + A4 * sh_dv[p][4] + A5 * sh_dv[p][5];
            #pragma unroll
            for (int k = 0; k < 8; ++k)
                a += sh_wk[p][k] * b2f(P[((size_t)(k * NIN + sh_ipos[p][k])) * 256 + o]);
            zs[p * 256 + o] = a;
        }
    }
    __syncthreads();

    // ---- stage 3: h[p][j] = gelu(fc1 . z + b), 16 positions per weight load ----
    {
        const int j = tid;
        float acc[16];
        const float fb = F[F_FC1B + j];
        #pragma unroll
        for (int p = 0; p < 16; ++p) acc[p] = fb;
        for (int o = 0; o < 256; o += 4) {
            const float wv0 = b2f(fc1T[(o + 0) * 256 + j]);
            const float wv1 = b2f(fc1T[(o + 1) * 256 + j]);
            const float wv2 = b2f(fc1T[(o + 2) * 256 + j]);
            const float wv3 = b2f(fc1T[(o + 3) * 256 + j]);
            #pragma unroll
            for (int p = 0; p < 16; ++p) {
                const float4 z4 = *reinterpret_cast<const float4*>(&zs[p * 256 + o]);
                acc[p] = fmaf(wv0, z4.x, fmaf(wv1, z4.y, fmaf(wv2, z4.z, fmaf(wv3, z4.w, acc[p]))));
            }
        }
        __syncthreads();   // all reads of zs done before overwrite
        #pragma unroll
        for (int p = 0; p < 16; ++p) {
            const float x = acc[p];
            zs[p * 256 + j] = 0.5f * x * (1.0f + erff(x * 0.70710678118654752f)); // exact gelu
        }
    }
    __syncthreads();

    // ---- stage 4: fc2 + shortcut + store ----
    if (tid < 48) {
        const int p = tid / 3, jj = tid - 3 * p;
        float a = F[F_FC2B + jj];
        const float* wrow = F + F_FC2W + jj * 256;
        for (int o = 0; o < 256; ++o) a += wrow[o] * zs[p * 256 + o];
        a += sh_g[jj][p];
        const int oidx = jj * NOUT + pos0 + p;
        if (f32) ((float*)outv)[oidx] = a;
        else     ((bf16*)outv)[oidx] = f2b(a);
    }
}

extern "C" void kernel_launch(void* const* d_in, const int* in_sizes, int n_in,
                              void* d_out, int out_size, void* d_ws, size_t ws_size,
                              hipStream_t stream) {
    const void* feat    = d_in[0];
    const void* dw1_w   = d_in[1];
    const void* dw1_b   = d_in[2];
    const void* pw1_w   = d_in[3];
    const void* pw1_b   = d_in[4];
    const void* fc1_w   = d_in[5];
    const void* fc1_b   = d_in[6];
    const void* fc2_w   = d_in[7];
    const void* fc2_b   = d_in[8];
    const void* sc_dw_w = d_in[9];
    const void* sc_dw_b = d_in[10];
    const void* sc_pw_w = d_in[11];
    const void* sc_pw_b = d_in[12];

    const size_t P_BYTES = (size_t)8 * NIN * 256 * 2;   // 39,321,600
    const size_t FC1T_BYTES = (size_t)256 * 256 * 2;    // 131,072
    bf16*  P    = (bf16*)d_ws;
    bf16*  fc1T = (bf16*)((char*)d_ws + P_BYTES);
    float* F    = (float*)((char*)d_ws + P_BYTES + FC1T_BYTES);
    int*   I    = (int*)(F + F_END);
    // total ws need ~40.2 MB

    k_prep<<<1, 256, 0, stream>>>(feat, dw1_w, dw1_b, pw1_w, pw1_b, fc1_w, fc1_b,
                                  fc2_w, fc2_b, sc_dw_w, sc_dw_b, sc_pw_w, sc_pw_b,
                                  fc1T, F, I);
    k_corner<<<NIN / 16, 256, 0, stream>>>(feat, F, I, P);
    k_main<<<NOUT / 16, 256, 0, stream>>>(P, fc1T, F, I, (void*)d_out);
}

// Round 3
// 381.388 us; speedup vs baseline: 1.5952x; 1.5952x over previous
//
#include <hip/hip_runtime.h>
#include <hip/hip_bf16.h>

using bf16 = __hip_bfloat16;

__device__ __forceinline__ float b2f(bf16 x) { return __bfloat162float(x); }
__device__ __forceinline__ bf16  f2b(float x) { return __float2bfloat16(x); }
// flag-dispatched input load: f32==1 -> fp32 storage, else bf16 storage
__device__ __forceinline__ float ldin(const void* p, int i, int f32) {
    return f32 ? ((const float*)p)[i] : b2f(((const bf16*)p)[i]);
}

// problem dims (fixed by setup_inputs)
#define TI 6
#define HI 40
#define WI 40
#define TO 12
#define HO 80
#define WO 80
#define NIN (TI*HI*WI)    // 9600
#define NOUT (TO*HO*WO)   // 76800

// ---------------- workspace layout ----------------
// [0, P_BYTES)                : P bf16 [8][NIN][256]   (corner projections)
// [P_BYTES, +FC1T_BYTES)      : fc1T bf16 [256][256]   (fc1_w transposed)
// float region F (offsets in floats):
#define F_W1F   0                       // [8*64][256] pw1_w(feat cols)*dw1_w, [k*64+c][o]
#define F_B1    (F_W1F + 8*64*256)      // [256] effective bias
#define F_ACO   (F_B1 + 256)            // [6][256] rel-coord coefficients
#define F_SCW   (F_ACO + 6*256)         // [3][64] sc_pw_w*sc_dw_w
#define F_SCB   (F_SCW + 3*64)          // [3] folded sc bias (pad 4)
#define F_SC    (F_SCB + 4)             // [3][NIN] shortcut conv output
#define F_DT    (F_SC + 3*NIN)          // [2][TO] signed d (t axis)
#define F_DH    (F_DT + 2*TO)           // [2][HO]
#define F_DW    (F_DH + 2*HO)           // [2][WO]
#define F_FT    (F_DW + 2*WO)           // [TO] trilinear frac
#define F_FH    (F_FT + TO)             // [HO]
#define F_FW    (F_FH + HO)             // [WO]
#define F_FC1B  (F_FW + WO)             // [256] fc1 bias (fp32 staged)
#define F_FC2W  (F_FC1B + 256)          // [3*256] fc2 weights (fp32 staged)
#define F_FC2B  (F_FC2W + 768)          // [3] fc2 bias (pad 4)
#define F_END   (F_FC2B + 4)
// int region I (offsets in ints), starts right after F region:
#define I_IT    0                       // [2][TO] nearest idx
#define I_IH    (I_IT + 2*TO)           // [2][HO]
#define I_IW    (I_IH + 2*HO)           // [2][WO]
#define I_LT0   (I_IW + 2*WO)           // [TO] trilinear i0
#define I_LT1   (I_LT0 + TO)
#define I_LH0   (I_LT1 + TO)
#define I_LH1   (I_LH0 + HO)
#define I_LW0   (I_LH1 + HO)
#define I_LW1   (I_LW0 + WO)
#define I_FLAG  (I_LW1 + WO)            // [1] 1 = fp32 storage, 0 = bf16 storage
#define I_END   (I_FLAG + 1)

// per-axis tables, replicating reference `near` (eps=1e-6, round-half-even) and `lin_idx`
__device__ __forceinline__ void axis_tables(int i, int n_out, int n_in,
                                            float* dvals, int* ivals,
                                            int* l0, int* l1, float* fr) {
    const float r_out = 1.0f / (float)n_out;
    const float r_in  = 1.0f / (float)n_in;
    const float c = -1.0f + r_out + 2.0f * r_out * (float)i;
    #pragma unroll
    for (int v = 0; v < 2; ++v) {
        const float vv = v ? 1.0f : -1.0f;
        float cc = c + vv * r_in + 1e-6f;
        cc = fminf(fmaxf(cc, -1.0f + 1e-6f), 1.0f - 1e-6f);
        float fx = rintf(((cc + 1.0f) * (float)n_in - 1.0f) * 0.5f);
        fx = fminf(fmaxf(fx, 0.0f), (float)(n_in - 1));
        const int idx = (int)fx;
        const float l = -1.0f + r_in + 2.0f * r_in * (float)idx;
        dvals[v * n_out + i] = (c - l) * (float)n_in;
        ivals[v * n_out + i] = idx;
    }
    float x = fminf(fmaxf(((c + 1.0f) * (float)n_in - 1.0f) * 0.5f, 0.0f), (float)(n_in - 1));
    const float x0 = floorf(x);
    fr[i] = x - x0;
    const int i0 = (int)x0;
    l0[i] = i0;
    l1[i] = min(i0 + 1, n_in - 1);
}

// ---------------- kernel A0: dtype detect + tables + small folds (1 block) ----------------
__global__ __launch_bounds__(256)
void k_prep0(const void* __restrict__ feat,
             const void* __restrict__ fc1_b,
             const void* __restrict__ fc2_w, const void* __restrict__ fc2_b,
             const void* __restrict__ sc_dw_w, const void* __restrict__ sc_dw_b,
             const void* __restrict__ sc_pw_w, const void* __restrict__ sc_pw_b,
             float* __restrict__ F, int* __restrict__ I) {
    const int tid = threadIdx.x;
    __shared__ int sflag;
    if (tid == 0) {
        // storage detection: even halfwords of fp32 data are mantissa junk
        // (~15% have a plausible bf16 exponent); of bf16 data they are real
        // bf16 samples (~100%). bf16-rounded-fp32 gives all-zero low halves.
        const unsigned short* u = (const unsigned short*)feat;
        int cnt = 0;
        for (int i = 0; i < 256; i += 2) {
            const unsigned e = (u[i] >> 7) & 0xFF;
            cnt += (e >= 0x68 && e <= 0x8E) ? 1 : 0;
        }
        sflag = (cnt < 64) ? 1 : 0;
        I[I_FLAG] = sflag;
    }
    __syncthreads();
    const int f32 = sflag;
    const int o = tid;

    // fp32-staged small tensors for k_main
    F[F_FC1B + o] = ldin(fc1_b, o, f32);
    for (int r = o; r < 768; r += 256) F[F_FC2W + r] = ldin(fc2_w, r, f32);
    if (o < 3) F[F_FC2B + o] = ldin(fc2_b, o, f32);

    // shortcut folded weights
    if (tid < 3) {
        const int j = tid;
        float s = ldin(sc_pw_b, j, f32);
        for (int c = 0; c < 64; ++c) {
            const float pw = ldin(sc_pw_w, j * 64 + c, f32);
            F[F_SCW + j * 64 + c] = pw * ldin(sc_dw_w, c, f32);
            s += pw * ldin(sc_dw_b, c, f32);
        }
        F[F_SCB + j] = s;
    }

    // axis tables
    if (tid < TO) axis_tables(tid, TO, TI, F + F_DT, I + I_IT, I + I_LT0, I + I_LT1, F + F_FT);
    if (tid < HO) axis_tables(tid, HO, HI, F + F_DH, I + I_IH, I + I_LH0, I + I_LH1, F + F_FH);
    if (tid < WO) axis_tables(tid, WO, WI, F + F_DW, I + I_IW, I + I_LW0, I + I_LW1, F + F_FW);
}

// ---------------- kernel A1: per-channel weight folding (256 blocks) ----------------
// block = output channel o. Coalesced row staging into LDS, then fold.
__global__ __launch_bounds__(256)
void k_fold(const void* __restrict__ dw1_w, const void* __restrict__ dw1_b,
            const void* __restrict__ pw1_w, const void* __restrict__ pw1_b,
            const void* __restrict__ fc1_w,
            bf16* __restrict__ fc1T, float* __restrict__ F,
            const int* __restrict__ I) {
    const int tid = threadIdx.x;
    const int o = blockIdx.x;
    const int f32 = I[I_FLAG];

    __shared__ float row[539];
    __shared__ float red[256];

    // stage pw1_w row o (coalesced)
    for (int ch = tid; ch < 539; ch += 256) row[ch] = ldin(pw1_w, o * 539 + ch, f32);
    __syncthreads();

    // W1f[cc][o] = row[24+cc] * dw1_w[24+cc]
    for (int cc = tid; cc < 512; cc += 256)
        F[F_W1F + cc * 256 + o] = row[24 + cc] * ldin(dw1_w, 24 + cc, f32);

    // fc1T[i][o] = fc1_w[o][i]  (coalesced read, scattered write)
    fc1T[tid * 256 + o] = f2b(ldin(fc1_w, o * 256 + tid, f32));

    // B1 partial reduce: sum row[ch]*dw1_b[ch]
    float s = 0.f;
    for (int ch = tid; ch < 539; ch += 256) s += row[ch] * ldin(dw1_b, ch, f32);
    red[tid] = s;
    __syncthreads();
    for (int st = 128; st > 0; st >>= 1) {
        if (tid < st) red[tid] += red[tid + st];
        __syncthreads();
    }

    if (tid == 0) {
        float bacc = ldin(pw1_b, o, f32) + red[0];
        #pragma unroll
        for (int ch = 536; ch < 539; ++ch)
            bacc += 2.0f * row[ch] * ldin(dw1_w, ch, f32);
        F[F_B1 + o] = bacc;

        // rel-coord coefficients: corner k has channels 3k(dct),3k+1(dch),3k+2(dcw)
        float A[6] = {0.f, 0.f, 0.f, 0.f, 0.f, 0.f};
        #pragma unroll
        for (int k = 0; k < 8; ++k) {
            A[(k >> 2)]           += row[3*k + 0] * ldin(dw1_w, 3*k + 0, f32);
            A[2 + ((k >> 1) & 1)] += row[3*k + 1] * ldin(dw1_w, 3*k + 1, f32);
            A[4 + (k & 1)]        += row[3*k + 2] * ldin(dw1_w, 3*k + 2, f32);
        }
        #pragma unroll
        for (int i = 0; i < 6; ++i) F[F_ACO + i * 256 + o] = A[i];
    }
}

// ---------------- kernel B: corner projections P + shortcut sc ----------------
__global__ __launch_bounds__(256)
void k_corner(const void* __restrict__ feat, float* __restrict__ F,
              const int* __restrict__ I, bf16* __restrict__ P) {
    const int tid = threadIdx.x;
    const int pos0 = blockIdx.x * 16;
    const int f32 = I[I_FLAG];
    __shared__ float flds[64][16];   // [c][p]

    for (int idx = tid; idx < 1024; idx += 256) {
        const int c = idx >> 4, p = idx & 15;
        flds[c][p] = ldin(feat, c * NIN + pos0 + p, f32);
    }
    __syncthreads();

    const int o = tid;
    for (int k = 0; k < 8; ++k) {
        float acc[16];
        #pragma unroll
        for (int p = 0; p < 16; ++p) acc[p] = 0.f;
        const float* Wk = F + F_W1F + (k << 6) * 256 + o;
        #pragma unroll 8
        for (int c = 0; c < 64; ++c) {
            const float wv = Wk[c * 256];
            #pragma unroll
            for (int p = 0; p < 16; ++p) acc[p] += wv * flds[c][p];
        }
        bf16* Pk = P + ((size_t)(k * NIN + pos0)) * 256 + o;
        #pragma unroll
        for (int p = 0; p < 16; ++p) Pk[(size_t)p * 256] = f2b(acc[p]);
    }

    // shortcut: sc[j][pos] = sum_c feat*scw + scb
    if (tid < 48) {
        const int j = tid >> 4, p = tid & 15;
        float s = F[F_SCB + j];
        for (int c = 0; c < 64; ++c) s += flds[c][p] * F[F_SCW + j * 64 + c];
        F[F_SC + j * NIN + pos0 + p] = s;
    }
}

// ---------------- kernel C: main fused MLP + trilinear shortcut ----------------
__global__ __launch_bounds__(256)
void k_main(const bf16* __restrict__ P, const bf16* __restrict__ fc1T,
            const float* __restrict__ F, const int* __restrict__ I,
            void* __restrict__ outv) {
    const int tid = threadIdx.x;
    const int pos0 = blockIdx.x * 16;              // 16 consecutive w within one (t,h) row
    const int t = pos0 / (HO * WO);
    const int rem = pos0 - t * (HO * WO);
    const int h = rem / WO;
    const int w0 = rem - h * WO;
    const int f32 = I[I_FLAG];

    __shared__ __align__(16) float zs[16 * 256];   // [p][o], reused for gelu(h) after sync
    __shared__ int   sh_ipos[16][8];
    __shared__ float sh_wk[16][8];
    __shared__ float sh_dv[16][6];
    __shared__ float sh_g[3][16];

    // ---- stage 1: per-position scalars (threads 0..15) ----
    if (tid < 16) {
        const int p = tid;
        const int w = w0 + p;
        const int   iTa[2] = { I[I_IT + t], I[I_IT + TO + t] };
        const float dTv[2] = { F[F_DT + t], F[F_DT + TO + t] };
        const int   iHa[2] = { I[I_IH + h], I[I_IH + HO + h] };
        const float dHv[2] = { F[F_DH + h], F[F_DH + HO + h] };
        const int   iWa[2] = { I[I_IW + w], I[I_IW + WO + w] };
        const float dWv[2] = { F[F_DW + w], F[F_DW + WO + w] };
        sh_dv[p][0] = dTv[0]; sh_dv[p][1] = dTv[1];
        sh_dv[p][2] = dHv[0]; sh_dv[p][3] = dHv[1];
        sh_dv[p][4] = dWv[0]; sh_dv[p][5] = dWv[1];
        const float aT[2] = { fabsf(dTv[0]), fabsf(dTv[1]) };
        const float aH[2] = { fabsf(dHv[0]), fabsf(dHv[1]) };
        const float aW[2] = { fabsf(dWv[0]), fabsf(dWv[1]) };
        const float tot = (aT[0] + aT[1]) * (aH[0] + aH[1]) * (aW[0] + aW[1]) + 8e-9f;
        #pragma unroll
        for (int k = 0; k < 8; ++k) {
            const int at = k >> 2, ah = (k >> 1) & 1, aw = k & 1;
            sh_wk[p][k] = (aT[1 - at] * aH[1 - ah] * aW[1 - aw] + 1e-9f) / tot;
            sh_ipos[p][k] = iTa[at] * (HI * WI) + iHa[ah] * WI + iWa[aw];
        }
        // trilinear shortcut g
        const int a0 = I[I_LT0 + t], a1 = I[I_LT1 + t];
        const int bh0 = I[I_LH0 + h], bh1 = I[I_LH1 + h];
        const int c0 = I[I_LW0 + w], c1 = I[I_LW1 + w];
        const float fT = F[F_FT + t], fH = F[F_FH + h], fW = F[F_FW + w];
        #pragma unroll
        for (int jj = 0; jj < 3; ++jj) {
            const float* Sj = F + F_SC + jj * NIN;
            const int i0 = a0 * (HI * WI), i1 = a1 * (HI * WI);
            const float v000 = Sj[i0 + bh0 * WI + c0], v001 = Sj[i0 + bh0 * WI + c1];
            const float v010 = Sj[i0 + bh1 * WI + c0], v011 = Sj[i0 + bh1 * WI + c1];
            const float v100 = Sj[i1 + bh0 * WI + c0], v101 = Sj[i1 + bh0 * WI + c1];
            const float v110 = Sj[i1 + bh1 * WI + c0], v111 = Sj[i1 + bh1 * WI + c1];
            const float u00 = v000 * (1.f - fT) + v100 * fT;
            const float u01 = v001 * (1.f - fT) + v101 * fT;
            const float u10 = v010 * (1.f - fT) + v110 * fT;
            const float u11 = v011 * (1.f - fT) + v111 * fT;
            const float q0 = u00 * (1.f - fH) + u10 * fH;
            const float q1 = u01 * (1.f - fH) + u11 * fH;
            sh_g[jj][p] = q0 * (1.f - fW) + q1 * fW;
        }
    }
    __syncthreads();

    // ---- stage 2: z[p][o] = b1eff + Acoef·dv + sum_k wk * P[k][ipos][o] ----
    {
        const int o = tid;
        const float bz = F[F_B1 + o];
        const float A0 = F[F_ACO + 0 * 256 + o], A1 = F[F_ACO + 1 * 256 + o];
        const float A2 = F[F_ACO + 2 * 256 + o], A3 = F[F_ACO + 3 * 256 + o];
        const float A4 = F[F_ACO + 4 * 256 + o], A5 = F[F_ACO + 5 * 256 + o];
        #pragma unroll
        for (int p = 0; p < 16; ++p) {
            float a = bz + A0 * sh_dv[p][0] + A1 * sh_dv[p][1] + A2 * sh_dv[p][2]
                         + A3 * sh_dv[p][3] + A4 * sh_dv[p][4] + A5 * sh_dv[p][5];
            #pragma unroll
            for (int k = 0; k < 8; ++k)
                a += sh_wk[p][k] * b2f(P[((size_t)(k * NIN + sh_ipos[p][k])) * 256 + o]);
            zs[p * 256 + o] = a;
        }
    }
    __syncthreads();

    // ---- stage 3: h[p][j] = gelu(fc1 . z + b), 16 positions per weight load ----
    {
        const int j = tid;
        float acc[16];
        const float fb = F[F_FC1B + j];
        #pragma unroll
        for (int p = 0; p < 16; ++p) acc[p] = fb;
        for (int o = 0; o < 256; o += 4) {
            const float wv0 = b2f(fc1T[(o + 0) * 256 + j]);
            const float wv1 = b2f(fc1T[(o + 1) * 256 + j]);
            const float wv2 = b2f(fc1T[(o + 2) * 256 + j]);
            const float wv3 = b2f(fc1T[(o + 3) * 256 + j]);
            #pragma unroll
            for (int p = 0; p < 16; ++p) {
                const float4 z4 = *reinterpret_cast<const float4*>(&zs[p * 256 + o]);
                acc[p] = fmaf(wv0, z4.x, fmaf(wv1, z4.y, fmaf(wv2, z4.z, fmaf(wv3, z4.w, acc[p]))));
            }
        }
        __syncthreads();   // all reads of zs done before overwrite
        #pragma unroll
        for (int p = 0; p < 16; ++p) {
            const float x = acc[p];
            zs[p * 256 + j] = 0.5f * x * (1.0f + erff(x * 0.70710678118654752f)); // exact gelu
        }
    }
    __syncthreads();

    // ---- stage 4: fc2 + shortcut + store ----
    if (tid < 48) {
        const int p = tid / 3, jj = tid - 3 * p;
        float a = F[F_FC2B + jj];
        const float* wrow = F + F_FC2W + jj * 256;
        for (int o = 0; o < 256; ++o) a += wrow[o] * zs[p * 256 + o];
        a += sh_g[jj][p];
        const int oidx = jj * NOUT + pos0 + p;
        if (f32) ((float*)outv)[oidx] = a;
        else     ((bf16*)outv)[oidx] = f2b(a);
    }
}

extern "C" void kernel_launch(void* const* d_in, const int* in_sizes, int n_in,
                              void* d_out, int out_size, void* d_ws, size_t ws_size,
                              hipStream_t stream) {
    const void* feat    = d_in[0];
    const void* dw1_w   = d_in[1];
    const void* dw1_b   = d_in[2];
    const void* pw1_w   = d_in[3];
    const void* pw1_b   = d_in[4];
    const void* fc1_w   = d_in[5];
    const void* fc1_b   = d_in[6];
    const void* fc2_w   = d_in[7];
    const void* fc2_b   = d_in[8];
    const void* sc_dw_w = d_in[9];
    const void* sc_dw_b = d_in[10];
    const void* sc_pw_w = d_in[11];
    const void* sc_pw_b = d_in[12];

    const size_t P_BYTES = (size_t)8 * NIN * 256 * 2;   // 39,321,600
    const size_t FC1T_BYTES = (size_t)256 * 256 * 2;    // 131,072
    bf16*  P    = (bf16*)d_ws;
    bf16*  fc1T = (bf16*)((char*)d_ws + P_BYTES);
    float* F    = (float*)((char*)d_ws + P_BYTES + FC1T_BYTES);
    int*   I    = (int*)(F + F_END);
    // total ws need ~40.2 MB

    k_prep0<<<1, 256, 0, stream>>>(feat, fc1_b, fc2_w, fc2_b,
                                   sc_dw_w, sc_dw_b, sc_pw_w, sc_pw_b, F, I);
    k_fold<<<256, 256, 0, stream>>>(dw1_w, dw1_b, pw1_w, pw1_b, fc1_w, fc1T, F, I);
    k_corner<<<NIN / 16, 256, 0, stream>>>(feat, F, I, P);
    k_main<<<NOUT / 16, 256, 0, stream>>>(P, fc1T, F, I, (void*)d_out);
}

// Round 4
// 276.183 us; speedup vs baseline: 2.2028x; 1.3809x over previous
//
#include <hip/hip_runtime.h>
#include <hip/hip_bf16.h>

using bf16 = __hip_bfloat16;
typedef __attribute__((ext_vector_type(8))) short short8x;   // 8 bf16 (4 VGPRs)
typedef __attribute__((ext_vector_type(4))) float f32x4;     // MFMA accumulator

__device__ __forceinline__ float b2f(bf16 x) { return __bfloat162float(x); }
__device__ __forceinline__ bf16  f2b(float x) { return __float2bfloat16(x); }
__device__ __forceinline__ short bbits(float x) { bf16 b = f2b(x); short s; __builtin_memcpy(&s, &b, 2); return s; }
// flag-dispatched input load: f32==1 -> fp32 storage, else bf16 storage
__device__ __forceinline__ float ldin(const void* p, int i, int f32) {
    return f32 ? ((const float*)p)[i] : b2f(((const bf16*)p)[i]);
}

// problem dims (fixed by setup_inputs)
#define TI 6
#define HI 40
#define WI 40
#define TO 12
#define HO 80
#define WO 80
#define NIN (TI*HI*WI)    // 9600
#define NOUT (TO*HO*WO)   // 76800

// ---------------- workspace layout ----------------
// [0, P_BYTES)                : P bf16 [8][NIN][256]   (corner projections)
// [P_BYTES, +FC1P_BYTES)      : fc1P bf16 [8 kc][16 nt][64 lane][8] pre-packed B fragments
// float region F (offsets in floats):
#define F_W1F   0                       // [8*64][256] pw1_w(feat cols)*dw1_w, [k*64+c][o]
#define F_B1    (F_W1F + 8*64*256)      // [256] effective bias
#define F_ACO   (F_B1 + 256)            // [6][256] rel-coord coefficients
#define F_SCW   (F_ACO + 6*256)         // [3][64] sc_pw_w*sc_dw_w
#define F_SCB   (F_SCW + 3*64)          // [3] folded sc bias (pad 4)
#define F_SC    (F_SCB + 4)             // [3][NIN] shortcut conv output
#define F_DT    (F_SC + 3*NIN)          // [2][TO] signed d (t axis)
#define F_DH    (F_DT + 2*TO)           // [2][HO]
#define F_DW    (F_DH + 2*HO)           // [2][WO]
#define F_FT    (F_DW + 2*WO)           // [TO] trilinear frac
#define F_FH    (F_FT + TO)             // [HO]
#define F_FW    (F_FH + HO)             // [WO]
#define F_FC1B  (F_FW + WO)             // [256] fc1 bias (fp32 staged)
#define F_FC2W  (F_FC1B + 256)          // [3*256] fc2 weights (fp32 staged)
#define F_FC2B  (F_FC2W + 768)          // [3] fc2 bias (pad 4)
#define F_END   (F_FC2B + 4)
// int region I (offsets in ints), starts right after F region:
#define I_IT    0                       // [2][TO] nearest idx
#define I_IH    (I_IT + 2*TO)           // [2][HO]
#define I_IW    (I_IH + 2*HO)           // [2][WO]
#define I_LT0   (I_IW + 2*WO)           // [TO] trilinear i0
#define I_LT1   (I_LT0 + TO)
#define I_LH0   (I_LT1 + TO)
#define I_LH1   (I_LH0 + HO)
#define I_LW0   (I_LH1 + HO)
#define I_LW1   (I_LW0 + WO)
#define I_FLAG  (I_LW1 + WO)            // [1] 1 = fp32 storage, 0 = bf16 storage
#define I_END   (I_FLAG + 1)

#define ZPAD 264   // bf16 row stride for z LDS tiles (+8 pad -> 2-way-max conflicts on b128)
#define HPAD 260   // fp32 row stride for h LDS tile

// per-axis tables, replicating reference `near` (eps=1e-6, round-half-even) and `lin_idx`
__device__ __forceinline__ void axis_tables(int i, int n_out, int n_in,
                                            float* dvals, int* ivals,
                                            int* l0, int* l1, float* fr) {
    const float r_out = 1.0f / (float)n_out;
    const float r_in  = 1.0f / (float)n_in;
    const float c = -1.0f + r_out + 2.0f * r_out * (float)i;
    #pragma unroll
    for (int v = 0; v < 2; ++v) {
        const float vv = v ? 1.0f : -1.0f;
        float cc = c + vv * r_in + 1e-6f;
        cc = fminf(fmaxf(cc, -1.0f + 1e-6f), 1.0f - 1e-6f);
        float fx = rintf(((cc + 1.0f) * (float)n_in - 1.0f) * 0.5f);
        fx = fminf(fmaxf(fx, 0.0f), (float)(n_in - 1));
        const int idx = (int)fx;
        const float l = -1.0f + r_in + 2.0f * r_in * (float)idx;
        dvals[v * n_out + i] = (c - l) * (float)n_in;
        ivals[v * n_out + i] = idx;
    }
    float x = fminf(fmaxf(((c + 1.0f) * (float)n_in - 1.0f) * 0.5f, 0.0f), (float)(n_in - 1));
    const float x0 = floorf(x);
    fr[i] = x - x0;
    const int i0 = (int)x0;
    l0[i] = i0;
    l1[i] = min(i0 + 1, n_in - 1);
}

// ---------------- kernel A0: dtype detect + tables + small folds (1 block) ----------------
__global__ __launch_bounds__(256)
void k_prep0(const void* __restrict__ feat,
             const void* __restrict__ fc1_b,
             const void* __restrict__ fc2_w, const void* __restrict__ fc2_b,
             const void* __restrict__ sc_dw_w, const void* __restrict__ sc_dw_b,
             const void* __restrict__ sc_pw_w, const void* __restrict__ sc_pw_b,
             float* __restrict__ F, int* __restrict__ I) {
    const int tid = threadIdx.x;
    __shared__ int sflag;
    if (tid == 0) {
        // storage detection: even halfwords of fp32 data are mantissa junk
        // (~15% have a plausible bf16 exponent); of bf16 data they are real
        // bf16 samples (~100%). bf16-rounded-fp32 gives all-zero low halves.
        const unsigned short* u = (const unsigned short*)feat;
        int cnt = 0;
        for (int i = 0; i < 256; i += 2) {
            const unsigned e = (u[i] >> 7) & 0xFF;
            cnt += (e >= 0x68 && e <= 0x8E) ? 1 : 0;
        }
        sflag = (cnt < 64) ? 1 : 0;
        I[I_FLAG] = sflag;
    }
    __syncthreads();
    const int f32 = sflag;
    const int o = tid;

    // fp32-staged small tensors for k_main
    F[F_FC1B + o] = ldin(fc1_b, o, f32);
    for (int r = o; r < 768; r += 256) F[F_FC2W + r] = ldin(fc2_w, r, f32);
    if (o < 3) F[F_FC2B + o] = ldin(fc2_b, o, f32);

    // shortcut folded weights
    if (tid < 3) {
        const int j = tid;
        float s = ldin(sc_pw_b, j, f32);
        for (int c = 0; c < 64; ++c) {
            const float pw = ldin(sc_pw_w, j * 64 + c, f32);
            F[F_SCW + j * 64 + c] = pw * ldin(sc_dw_w, c, f32);
            s += pw * ldin(sc_dw_b, c, f32);
        }
        F[F_SCB + j] = s;
    }

    // axis tables
    if (tid < TO) axis_tables(tid, TO, TI, F + F_DT, I + I_IT, I + I_LT0, I + I_LT1, F + F_FT);
    if (tid < HO) axis_tables(tid, HO, HI, F + F_DH, I + I_IH, I + I_LH0, I + I_LH1, F + F_FH);
    if (tid < WO) axis_tables(tid, WO, WI, F + F_DW, I + I_IW, I + I_LW0, I + I_LW1, F + F_FW);
}

// ---------------- kernel A1: per-channel weight folding (256 blocks) ----------------
__global__ __launch_bounds__(256)
void k_fold(const void* __restrict__ dw1_w, const void* __restrict__ dw1_b,
            const void* __restrict__ pw1_w, const void* __restrict__ pw1_b,
            float* __restrict__ F, const int* __restrict__ I) {
    const int tid = threadIdx.x;
    const int o = blockIdx.x;
    const int f32 = I[I_FLAG];

    __shared__ float row[539];
    __shared__ float red[256];

    for (int ch = tid; ch < 539; ch += 256) row[ch] = ldin(pw1_w, o * 539 + ch, f32);
    __syncthreads();

    for (int cc = tid; cc < 512; cc += 256)
        F[F_W1F + cc * 256 + o] = row[24 + cc] * ldin(dw1_w, 24 + cc, f32);

    float s = 0.f;
    for (int ch = tid; ch < 539; ch += 256) s += row[ch] * ldin(dw1_b, ch, f32);
    red[tid] = s;
    __syncthreads();
    for (int st = 128; st > 0; st >>= 1) {
        if (tid < st) red[tid] += red[tid + st];
        __syncthreads();
    }

    if (tid == 0) {
        float bacc = ldin(pw1_b, o, f32) + red[0];
        #pragma unroll
        for (int ch = 536; ch < 539; ++ch)
            bacc += 2.0f * row[ch] * ldin(dw1_w, ch, f32);
        F[F_B1 + o] = bacc;

        float A[6] = {0.f, 0.f, 0.f, 0.f, 0.f, 0.f};
        #pragma unroll
        for (int k = 0; k < 8; ++k) {
            A[(k >> 2)]           += row[3*k + 0] * ldin(dw1_w, 3*k + 0, f32);
            A[2 + ((k >> 1) & 1)] += row[3*k + 1] * ldin(dw1_w, 3*k + 1, f32);
            A[4 + (k & 1)]        += row[3*k + 2] * ldin(dw1_w, 3*k + 2, f32);
        }
        #pragma unroll
        for (int i = 0; i < 6; ++i) F[F_ACO + i * 256 + o] = A[i];
    }
}

// ---------------- kernel A2: pre-pack fc1 into MFMA B-fragment order ----------------
// fc1P[((kc*16 + nt)*64 + lane)*8 + jj] = fc1_w[n][k], n = nt*16 + (lane&15),
// k = kc*32 + (lane>>4)*8 + jj  (B[k][n] fragment for mfma_f32_16x16x32_bf16)
__global__ __launch_bounds__(256)
void k_pack(const void* __restrict__ fc1_w, bf16* __restrict__ fc1P,
            const int* __restrict__ I) {
    const int f32 = I[I_FLAG];
    const int g = blockIdx.x * 256 + threadIdx.x;    // 0..8191
    const int kc = g >> 10;
    const int nt = (g >> 6) & 15;
    const int wl = g & 63;
    const int n = nt * 16 + (wl & 15);
    const int k0 = kc * 32 + (wl >> 4) * 8;
    bf16 v[8];
    #pragma unroll
    for (int jj = 0; jj < 8; ++jj) v[jj] = f2b(ldin(fc1_w, n * 256 + k0 + jj, f32));
    *(short8x*)&fc1P[(size_t)g * 8] = *(short8x*)v;
}

// ---------------- kernel B: corner projections P + shortcut sc ----------------
__global__ __launch_bounds__(256)
void k_corner(const void* __restrict__ feat, float* __restrict__ F,
              const int* __restrict__ I, bf16* __restrict__ P) {
    const int tid = threadIdx.x;
    const int pos0 = blockIdx.x * 16;
    const int f32 = I[I_FLAG];
    __shared__ float flds[64][16];   // [c][p]

    for (int idx = tid; idx < 1024; idx += 256) {
        const int c = idx >> 4, p = idx & 15;
        flds[c][p] = ldin(feat, c * NIN + pos0 + p, f32);
    }
    __syncthreads();

    const int o = tid;
    for (int k = 0; k < 8; ++k) {
        float acc[16];
        #pragma unroll
        for (int p = 0; p < 16; ++p) acc[p] = 0.f;
        const float* Wk = F + F_W1F + (k << 6) * 256 + o;
        #pragma unroll 8
        for (int c = 0; c < 64; ++c) {
            const float wv = Wk[c * 256];
            #pragma unroll
            for (int p = 0; p < 16; ++p) acc[p] += wv * flds[c][p];
        }
        bf16* Pk = P + ((size_t)(k * NIN + pos0)) * 256 + o;
        #pragma unroll
        for (int p = 0; p < 16; ++p) Pk[(size_t)p * 256] = f2b(acc[p]);
    }

    if (tid < 48) {
        const int j = tid >> 4, p = tid & 15;
        float s = F[F_SCB + j];
        for (int c = 0; c < 64; ++c) s += flds[c][p] * F[F_SCW + j * 64 + c];
        F[F_SC + j * NIN + pos0 + p] = s;
    }
}

// ---------------- kernel C: main fused MLP (MFMA fc1) + trilinear shortcut ----------------
__global__ __launch_bounds__(256)
void k_main(const bf16* __restrict__ P, const bf16* __restrict__ fc1P,
            const float* __restrict__ F, const int* __restrict__ I,
            void* __restrict__ outv) {
    const int tid = threadIdx.x;
    const int pos0 = blockIdx.x * 16;              // 16 consecutive w within one (t,h) row
    const int t = pos0 / (HO * WO);
    const int rem = pos0 - t * (HO * WO);
    const int h = rem / WO;
    const int w0 = rem - h * WO;
    const int f32 = I[I_FLAG];

    __shared__ __align__(16) short zsh[16 * ZPAD];  // z high bf16 bits, [p][o]
    __shared__ __align__(16) short zsl[16 * ZPAD];  // z low-correction bf16 bits
    __shared__ float hs[16 * HPAD];                 // gelu(fc1 out), [p][j]
    __shared__ float red[16 * 3 * 16];              // fc2 partial reduce
    __shared__ int   sh_ipos[16][8];
    __shared__ float sh_wk[16][8];
    __shared__ float sh_dv[16][6];
    __shared__ float sh_g[3][16];

    // ---- stage 1: per-position scalars (threads 0..15) ----
    if (tid < 16) {
        const int p = tid;
        const int w = w0 + p;
        const int   iTa[2] = { I[I_IT + t], I[I_IT + TO + t] };
        const float dTv[2] = { F[F_DT + t], F[F_DT + TO + t] };
        const int   iHa[2] = { I[I_IH + h], I[I_IH + HO + h] };
        const float dHv[2] = { F[F_DH + h], F[F_DH + HO + h] };
        const int   iWa[2] = { I[I_IW + w], I[I_IW + WO + w] };
        const float dWv[2] = { F[F_DW + w], F[F_DW + WO + w] };
        sh_dv[p][0] = dTv[0]; sh_dv[p][1] = dTv[1];
        sh_dv[p][2] = dHv[0]; sh_dv[p][3] = dHv[1];
        sh_dv[p][4] = dWv[0]; sh_dv[p][5] = dWv[1];
        const float aT[2] = { fabsf(dTv[0]), fabsf(dTv[1]) };
        const float aH[2] = { fabsf(dHv[0]), fabsf(dHv[1]) };
        const float aW[2] = { fabsf(dWv[0]), fabsf(dWv[1]) };
        const float tot = (aT[0] + aT[1]) * (aH[0] + aH[1]) * (aW[0] + aW[1]) + 8e-9f;
        #pragma unroll
        for (int k = 0; k < 8; ++k) {
            const int at = k >> 2, ah = (k >> 1) & 1, aw = k & 1;
            sh_wk[p][k] = (aT[1 - at] * aH[1 - ah] * aW[1 - aw] + 1e-9f) / tot;
            sh_ipos[p][k] = iTa[at] * (HI * WI) + iHa[ah] * WI + iWa[aw];
        }
        const int a0 = I[I_LT0 + t], a1 = I[I_LT1 + t];
        const int bh0 = I[I_LH0 + h], bh1 = I[I_LH1 + h];
        const int c0 = I[I_LW0 + w], c1 = I[I_LW1 + w];
        const float fT = F[F_FT + t], fH = F[F_FH + h], fW = F[F_FW + w];
        #pragma unroll
        for (int jj = 0; jj < 3; ++jj) {
            const float* Sj = F + F_SC + jj * NIN;
            const int i0 = a0 * (HI * WI), i1 = a1 * (HI * WI);
            const float v000 = Sj[i0 + bh0 * WI + c0], v001 = Sj[i0 + bh0 * WI + c1];
            const float v010 = Sj[i0 + bh1 * WI + c0], v011 = Sj[i0 + bh1 * WI + c1];
            const float v100 = Sj[i1 + bh0 * WI + c0], v101 = Sj[i1 + bh0 * WI + c1];
            const float v110 = Sj[i1 + bh1 * WI + c0], v111 = Sj[i1 + bh1 * WI + c1];
            const float u00 = v000 * (1.f - fT) + v100 * fT;
            const float u01 = v001 * (1.f - fT) + v101 * fT;
            const float u10 = v010 * (1.f - fT) + v110 * fT;
            const float u11 = v011 * (1.f - fT) + v111 * fT;
            const float q0 = u00 * (1.f - fH) + u10 * fH;
            const float q1 = u01 * (1.f - fH) + u11 * fH;
            sh_g[jj][p] = q0 * (1.f - fW) + q1 * fW;
        }
    }
    __syncthreads();

    // ---- stage 2: z[p][o] = b1eff + Acoef·dv + sum_k wk * P[k][ipos][o]; split bf16 hi/lo ----
    {
        const int o = tid;
        const float bz = F[F_B1 + o];
        const float A0 = F[F_ACO + 0 * 256 + o], A1 = F[F_ACO + 1 * 256 + o];
        const float A2 = F[F_ACO + 2 * 256 + o], A3 = F[F_ACO + 3 * 256 + o];
        const float A4 = F[F_ACO + 4 * 256 + o], A5 = F[F_ACO + 5 * 256 + o];
        #pragma unroll
        for (int p = 0; p < 16; ++p) {
            float a = bz + A0 * sh_dv[p][0] + A1 * sh_dv[p][1] + A2 * sh_dv[p][2]
                         + A3 * sh_dv[p][3] + A4 * sh_dv[p][4] + A5 * sh_dv[p][5];
            #pragma unroll
            for (int k = 0; k < 8; ++k)
                a += sh_wk[p][k] * b2f(P[((size_t)(k * NIN + sh_ipos[p][k])) * 256 + o]);
            const short hi = bbits(a);
            bf16 hb; __builtin_memcpy(&hb, &hi, 2);
            zsh[p * ZPAD + o] = hi;
            zsl[p * ZPAD + o] = bbits(a - b2f(hb));
        }
    }
    __syncthreads();

    // ---- stage 3: fc1 via MFMA 16x16x32 bf16, split hi/lo for fp32-grade accuracy ----
    // wave w handles output channels [w*64, w*64+64) = 4 N-tiles
    {
        const int wl = tid & 63, w = tid >> 6;
        const int col = wl & 15, quad = wl >> 4;
        f32x4 acc[4] = { {0,0,0,0}, {0,0,0,0}, {0,0,0,0}, {0,0,0,0} };
        const short8x* bp = (const short8x*)fc1P;
        #pragma unroll
        for (int kc = 0; kc < 8; ++kc) {
            // A frags: row p = col, k = kc*32 + quad*8 .. +7
            const short8x ah = *(const short8x*)&zsh[col * ZPAD + kc * 32 + quad * 8];
            const short8x al = *(const short8x*)&zsl[col * ZPAD + kc * 32 + quad * 8];
            #pragma unroll
            for (int nt = 0; nt < 4; ++nt) {
                const short8x b = bp[(kc * 16 + (w * 4 + nt)) * 64 + wl];
                acc[nt] = __builtin_amdgcn_mfma_f32_16x16x32_bf16(ah, b, acc[nt], 0, 0, 0);
                acc[nt] = __builtin_amdgcn_mfma_f32_16x16x32_bf16(al, b, acc[nt], 0, 0, 0);
            }
        }
        // D layout: m(pos) = quad*4 + r, n(channel) = w*64 + nt*16 + col
        #pragma unroll
        for (int nt = 0; nt < 4; ++nt) {
            const int j = w * 64 + nt * 16 + col;
            const float fb = F[F_FC1B + j];
            #pragma unroll
            for (int r = 0; r < 4; ++r) {
                const float x = acc[nt][r] + fb;
                hs[(quad * 4 + r) * HPAD + j] =
                    0.5f * x * (1.0f + erff(x * 0.70710678118654752f)); // exact gelu
            }
        }
    }
    __syncthreads();

    // ---- stage 4: fc2 (distributed) + shortcut + store ----
    {
        const int p = tid >> 4, sub = tid & 15;
        float p0 = 0.f, p1 = 0.f, p2 = 0.f;
        #pragma unroll
        for (int i = 0; i < 16; ++i) {
            const int o = sub * 16 + ((i + 2 * sub) & 15);   // rotation breaks bank aliasing
            const float hv = hs[p * HPAD + o];
            p0 += F[F_FC2W + 0 * 256 + o] * hv;
            p1 += F[F_FC2W + 1 * 256 + o] * hv;
            p2 += F[F_FC2W + 2 * 256 + o] * hv;
        }
        red[(p * 3 + 0) * 16 + sub] = p0;
        red[(p * 3 + 1) * 16 + sub] = p1;
        red[(p * 3 + 2) * 16 + sub] = p2;
    }
    __syncthreads();
    if (tid < 48) {
        const int p = tid / 3, jj = tid - 3 * p;
        float a = F[F_FC2B + jj];
        #pragma unroll
        for (int s = 0; s < 16; ++s) a += red[(p * 3 + jj) * 16 + s];
        a += sh_g[jj][p];
        const int oidx = jj * NOUT + pos0 + p;
        if (f32) ((float*)outv)[oidx] = a;
        else     ((bf16*)outv)[oidx] = f2b(a);
    }
}

extern "C" void kernel_launch(void* const* d_in, const int* in_sizes, int n_in,
                              void* d_out, int out_size, void* d_ws, size_t ws_size,
                              hipStream_t stream) {
    const void* feat    = d_in[0];
    const void* dw1_w   = d_in[1];
    const void* dw1_b   = d_in[2];
    const void* pw1_w   = d_in[3];
    const void* pw1_b   = d_in[4];
    const void* fc1_w   = d_in[5];
    const void* fc1_b   = d_in[6];
    const void* fc2_w   = d_in[7];
    const void* fc2_b   = d_in[8];
    const void* sc_dw_w = d_in[9];
    const void* sc_dw_b = d_in[10];
    const void* sc_pw_w = d_in[11];
    const void* sc_pw_b = d_in[12];

    const size_t P_BYTES = (size_t)8 * NIN * 256 * 2;   // 39,321,600
    const size_t FC1P_BYTES = (size_t)256 * 256 * 2;    // 131,072
    bf16*  P    = (bf16*)d_ws;
    bf16*  fc1P = (bf16*)((char*)d_ws + P_BYTES);
    float* F    = (float*)((char*)d_ws + P_BYTES + FC1P_BYTES);
    int*   I    = (int*)(F + F_END);
    // total ws need ~40.2 MB

    k_prep0<<<1, 256, 0, stream>>>(feat, fc1_b, fc2_w, fc2_b,
                                   sc_dw_w, sc_dw_b, sc_pw_w, sc_pw_b, F, I);
    k_fold<<<256, 256, 0, stream>>>(dw1_w, dw1_b, pw1_w, pw1_b, F, I);
    k_pack<<<32, 256, 0, stream>>>(fc1_w, fc1P, I);
    k_corner<<<NIN / 16, 256, 0, stream>>>(feat, F, I, P);
    k_main<<<NOUT / 16, 256, 0, stream>>>(P, fc1P, F, I, (void*)d_out);
}

// Round 5
// 211.086 us; speedup vs baseline: 2.8822x; 1.3084x over previous
//
#include <hip/hip_runtime.h>
#include <hip/hip_bf16.h>

using bf16 = __hip_bfloat16;
typedef __attribute__((ext_vector_type(8))) short short8x;            // 8 bf16 (4 VGPRs)
typedef __attribute__((ext_vector_type(4))) short short4x;            // 4 bf16
typedef __attribute__((ext_vector_type(4))) unsigned short ushort4x;  // 4 bf16 bits
typedef __attribute__((ext_vector_type(4))) float f32x4;              // MFMA accumulator

__device__ __forceinline__ float b2f(bf16 x) { return __bfloat162float(x); }
__device__ __forceinline__ bf16  f2b(float x) { return __float2bfloat16(x); }
__device__ __forceinline__ short bbits(float x) { bf16 b = f2b(x); short s; __builtin_memcpy(&s, &b, 2); return s; }
__device__ __forceinline__ float bu2f(unsigned short s) {
    unsigned v = ((unsigned)s) << 16; float f; __builtin_memcpy(&f, &v, 4); return f;
}
// flag-dispatched input load: f32==1 -> fp32 storage, else bf16 storage
__device__ __forceinline__ float ldin(const void* p, int i, int f32) {
    return f32 ? ((const float*)p)[i] : b2f(((const bf16*)p)[i]);
}

// problem dims (fixed by setup_inputs)
#define TI 6
#define HI 40
#define WI 40
#define TO 12
#define HO 80
#define WO 80
#define NIN (TI*HI*WI)    // 9600
#define NOUT (TO*HO*WO)   // 76800

// ---------------- workspace layout ----------------
// [0, P_BYTES)                : P bf16 [8][NIN][256]   (corner projections)
// [P_BYTES, +FC1P_BYTES)      : fc1P bf16 [8 kc][16 nt][64 lane][8] pre-packed B fragments
// float region F (offsets in floats):
#define F_W1F   0                       // [8*64][256] pw1_w(feat cols)*dw1_w, [k*64+c][o]
#define F_B1    (F_W1F + 8*64*256)      // [256] effective bias
#define F_ACO   (F_B1 + 256)            // [6][256] rel-coord coefficients
#define F_SCW   (F_ACO + 6*256)         // [3][64] sc_pw_w*sc_dw_w
#define F_SCB   (F_SCW + 3*64)          // [3] folded sc bias (pad 4)
#define F_SC    (F_SCB + 4)             // [3][NIN] shortcut conv output
#define F_DT    (F_SC + 3*NIN)          // [2][TO] signed d (t axis)
#define F_DH    (F_DT + 2*TO)           // [2][HO]
#define F_DW    (F_DH + 2*HO)           // [2][WO]
#define F_FT    (F_DW + 2*WO)           // [TO] trilinear frac
#define F_FH    (F_FT + TO)             // [HO]
#define F_FW    (F_FH + HO)             // [WO]
#define F_FC1B  (F_FW + WO)             // [256] fc1 bias (fp32 staged)
#define F_FC2W  (F_FC1B + 256)          // [3*256] fc2 weights (fp32 staged)
#define F_FC2B  (F_FC2W + 768)          // [3] fc2 bias (pad 4)
#define F_END   (F_FC2B + 4)
// int region I (offsets in ints), starts right after F region:
#define I_IT    0                       // [2][TO] nearest idx
#define I_IH    (I_IT + 2*TO)           // [2][HO]
#define I_IW    (I_IH + 2*HO)           // [2][WO]
#define I_LT0   (I_IW + 2*WO)           // [TO] trilinear i0
#define I_LT1   (I_LT0 + TO)
#define I_LH0   (I_LT1 + TO)
#define I_LH1   (I_LH0 + HO)
#define I_LW0   (I_LH1 + HO)
#define I_LW1   (I_LW0 + WO)
#define I_FLAG  (I_LW1 + WO)            // [1] 1 = fp32 storage, 0 = bf16 storage
#define I_END   (I_FLAG + 1)

#define MPOS 32     // positions per k_main block
#define ZPAD 264    // bf16 row stride for z LDS tile

// per-axis tables, replicating reference `near` (eps=1e-6, round-half-even) and `lin_idx`
__device__ __forceinline__ void axis_tables(int i, int n_out, int n_in,
                                            float* dvals, int* ivals,
                                            int* l0, int* l1, float* fr) {
    const float r_out = 1.0f / (float)n_out;
    const float r_in  = 1.0f / (float)n_in;
    const float c = -1.0f + r_out + 2.0f * r_out * (float)i;
    #pragma unroll
    for (int v = 0; v < 2; ++v) {
        const float vv = v ? 1.0f : -1.0f;
        float cc = c + vv * r_in + 1e-6f;
        cc = fminf(fmaxf(cc, -1.0f + 1e-6f), 1.0f - 1e-6f);
        float fx = rintf(((cc + 1.0f) * (float)n_in - 1.0f) * 0.5f);
        fx = fminf(fmaxf(fx, 0.0f), (float)(n_in - 1));
        const int idx = (int)fx;
        const float l = -1.0f + r_in + 2.0f * r_in * (float)idx;
        dvals[v * n_out + i] = (c - l) * (float)n_in;
        ivals[v * n_out + i] = idx;
    }
    float x = fminf(fmaxf(((c + 1.0f) * (float)n_in - 1.0f) * 0.5f, 0.0f), (float)(n_in - 1));
    const float x0 = floorf(x);
    fr[i] = x - x0;
    const int i0 = (int)x0;
    l0[i] = i0;
    l1[i] = min(i0 + 1, n_in - 1);
}

// ---------------- kernel A: merged setup (288 blocks) ----------------
// blocks 0..255: per-channel weight folding (o = blockIdx); block 0 also does
// tables/small folds. blocks 256..287: pack fc1 into MFMA B-fragment order:
// fc1P[((kc*16+nt)*64+wl)*8+jj] = fc1_w[n][k], n=nt*16+(wl&15), k=kc*32+(wl>>4)*8+jj
__global__ __launch_bounds__(256)
void k_setup(const void* __restrict__ feat,
             const void* __restrict__ dw1_w, const void* __restrict__ dw1_b,
             const void* __restrict__ pw1_w, const void* __restrict__ pw1_b,
             const void* __restrict__ fc1_w, const void* __restrict__ fc1_b,
             const void* __restrict__ fc2_w, const void* __restrict__ fc2_b,
             const void* __restrict__ sc_dw_w, const void* __restrict__ sc_dw_b,
             const void* __restrict__ sc_pw_w, const void* __restrict__ sc_pw_b,
             bf16* __restrict__ fc1P, float* __restrict__ F, int* __restrict__ I) {
    const int tid = threadIdx.x;
    const int b = blockIdx.x;
    __shared__ int sflag;
    // per-block dtype detection (wave-0 ballot): even halfwords of fp32 data
    // are mantissa junk (~15% in bf16-exponent window); of bf16 data ~100%.
    if (tid < 64) {
        const unsigned short* u = (const unsigned short*)feat;
        const unsigned e = (u[2 * tid] >> 7) & 0xFFu;
        const unsigned long long m = __ballot(e >= 0x68u && e <= 0x8Eu);
        if (tid == 0) sflag = (__popcll(m) < 32) ? 1 : 0;
    }
    __syncthreads();
    const int f32 = sflag;

    if (b >= 256) {           // ---- pack duty ----
        const int g = (b - 256) * 256 + tid;     // 0..8191
        const int kc = g >> 10, nt = (g >> 6) & 15, wl = g & 63;
        const int n = nt * 16 + (wl & 15);
        const int k0 = kc * 32 + (wl >> 4) * 8;
        bf16 v[8];
        #pragma unroll
        for (int jj = 0; jj < 8; ++jj) v[jj] = f2b(ldin(fc1_w, n * 256 + k0 + jj, f32));
        *(short8x*)&fc1P[(size_t)g * 8] = *(short8x*)v;
        return;
    }

    // ---- fold duty: output channel o = b ----
    __shared__ float row[539];
    __shared__ float red[256];
    const int o = b;

    for (int ch = tid; ch < 539; ch += 256) row[ch] = ldin(pw1_w, o * 539 + ch, f32);
    __syncthreads();

    for (int cc = tid; cc < 512; cc += 256)
        F[F_W1F + cc * 256 + o] = row[24 + cc] * ldin(dw1_w, 24 + cc, f32);

    float s = 0.f;
    for (int ch = tid; ch < 539; ch += 256) s += row[ch] * ldin(dw1_b, ch, f32);
    red[tid] = s;
    __syncthreads();
    for (int st = 128; st > 0; st >>= 1) {
        if (tid < st) red[tid] += red[tid + st];
        __syncthreads();
    }

    if (tid == 0) {
        float bacc = ldin(pw1_b, o, f32) + red[0];
        #pragma unroll
        for (int ch = 536; ch < 539; ++ch)
            bacc += 2.0f * row[ch] * ldin(dw1_w, ch, f32);
        F[F_B1 + o] = bacc;

        float A[6] = {0.f, 0.f, 0.f, 0.f, 0.f, 0.f};
        #pragma unroll
        for (int k = 0; k < 8; ++k) {
            A[(k >> 2)]           += row[3*k + 0] * ldin(dw1_w, 3*k + 0, f32);
            A[2 + ((k >> 1) & 1)] += row[3*k + 1] * ldin(dw1_w, 3*k + 1, f32);
            A[4 + (k & 1)]        += row[3*k + 2] * ldin(dw1_w, 3*k + 2, f32);
        }
        #pragma unroll
        for (int i = 0; i < 6; ++i) F[F_ACO + i * 256 + o] = A[i];
    }

    if (b == 0) {             // ---- prep0 duty (runs alongside fold in block 0) ----
        if (tid == 0) I[I_FLAG] = f32;
        F[F_FC1B + tid] = ldin(fc1_b, tid, f32);
        for (int r = tid; r < 768; r += 256) F[F_FC2W + r] = ldin(fc2_w, r, f32);
        if (tid < 3) F[F_FC2B + tid] = ldin(fc2_b, tid, f32);
        if (tid < 3) {
            const int j = tid;
            float sb = ldin(sc_pw_b, j, f32);
            for (int c = 0; c < 64; ++c) {
                const float pw = ldin(sc_pw_w, j * 64 + c, f32);
                F[F_SCW + j * 64 + c] = pw * ldin(sc_dw_w, c, f32);
                sb += pw * ldin(sc_dw_b, c, f32);
            }
            F[F_SCB + j] = sb;
        }
        if (tid < TO) axis_tables(tid, TO, TI, F + F_DT, I + I_IT, I + I_LT0, I + I_LT1, F + F_FT);
        if (tid < HO) axis_tables(tid, HO, HI, F + F_DH, I + I_IH, I + I_LH0, I + I_LH1, F + F_FH);
        if (tid < WO) axis_tables(tid, WO, WI, F + F_DW, I + I_IW, I + I_LW0, I + I_LW1, F + F_FW);
    }
}

// ---------------- kernel B: corner projections P + shortcut sc ----------------
__global__ __launch_bounds__(256)
void k_corner(const void* __restrict__ feat, float* __restrict__ F,
              const int* __restrict__ I, bf16* __restrict__ P) {
    const int tid = threadIdx.x;
    const int pos0 = blockIdx.x * 16;
    const int f32 = I[I_FLAG];
    __shared__ float flds[64][16];   // [c][p]

    for (int idx = tid; idx < 1024; idx += 256) {
        const int c = idx >> 4, p = idx & 15;
        flds[c][p] = ldin(feat, c * NIN + pos0 + p, f32);
    }
    __syncthreads();

    const int o = tid;
    for (int k = 0; k < 8; ++k) {
        float acc[16];
        #pragma unroll
        for (int p = 0; p < 16; ++p) acc[p] = 0.f;
        const float* Wk = F + F_W1F + (k << 6) * 256 + o;
        #pragma unroll 8
        for (int c = 0; c < 64; ++c) {
            const float wv = Wk[c * 256];
            #pragma unroll
            for (int p = 0; p < 16; ++p) acc[p] += wv * flds[c][p];
        }
        bf16* Pk = P + ((size_t)(k * NIN + pos0)) * 256 + o;
        #pragma unroll
        for (int p = 0; p < 16; ++p) Pk[(size_t)p * 256] = f2b(acc[p]);
    }

    if (tid < 48) {
        const int j = tid >> 4, p = tid & 15;
        float s = F[F_SCB + j];
        for (int c = 0; c < 64; ++c) s += flds[c][p] * F[F_SCW + j * 64 + c];
        F[F_SC + j * NIN + pos0 + p] = s;
    }
}

// ---------------- kernel C: main fused MLP (MFMA fc1, in-register fc2) ----------------
__global__ __launch_bounds__(256, 4)
void k_main(const bf16* __restrict__ P, const bf16* __restrict__ fc1P,
            const float* __restrict__ F, const int* __restrict__ I,
            void* __restrict__ outv) {
    const int tid = threadIdx.x;
    const int pos0 = blockIdx.x * MPOS;
    const int f32 = I[I_FLAG];

    __shared__ __align__(16) short zsh[MPOS * ZPAD];  // z bf16, [p][o]
    __shared__ float redc[MPOS * 4 * 3];              // fc2 per-wave partials [p][w][jj]
    __shared__ int   sh_ipos[MPOS][8];
    __shared__ float sh_wk[MPOS][8];
    __shared__ float sh_dv[MPOS][6];
    __shared__ float sh_g[3][MPOS];

    // ---- stage 1: per-position scalars (threads 0..31) ----
    if (tid < MPOS) {
        const int p = tid;
        const int pos = pos0 + p;
        const int t = pos / (HO * WO);
        const int rem = pos - t * (HO * WO);
        const int h = rem / WO;
        const int w = rem - h * WO;
        const int   iTa[2] = { I[I_IT + t], I[I_IT + TO + t] };
        const float dTv[2] = { F[F_DT + t], F[F_DT + TO + t] };
        const int   iHa[2] = { I[I_IH + h], I[I_IH + HO + h] };
        const float dHv[2] = { F[F_DH + h], F[F_DH + HO + h] };
        const int   iWa[2] = { I[I_IW + w], I[I_IW + WO + w] };
        const float dWv[2] = { F[F_DW + w], F[F_DW + WO + w] };
        sh_dv[p][0] = dTv[0]; sh_dv[p][1] = dTv[1];
        sh_dv[p][2] = dHv[0]; sh_dv[p][3] = dHv[1];
        sh_dv[p][4] = dWv[0]; sh_dv[p][5] = dWv[1];
        const float aT[2] = { fabsf(dTv[0]), fabsf(dTv[1]) };
        const float aH[2] = { fabsf(dHv[0]), fabsf(dHv[1]) };
        const float aW[2] = { fabsf(dWv[0]), fabsf(dWv[1]) };
        const float tot = (aT[0] + aT[1]) * (aH[0] + aH[1]) * (aW[0] + aW[1]) + 8e-9f;
        #pragma unroll
        for (int k = 0; k < 8; ++k) {
            const int at = k >> 2, ah = (k >> 1) & 1, aw = k & 1;
            sh_wk[p][k] = (aT[1 - at] * aH[1 - ah] * aW[1 - aw] + 1e-9f) / tot;
            sh_ipos[p][k] = iTa[at] * (HI * WI) + iHa[ah] * WI + iWa[aw];
        }
        // trilinear shortcut g
        const int a0 = I[I_LT0 + t], a1 = I[I_LT1 + t];
        const int bh0 = I[I_LH0 + h], bh1 = I[I_LH1 + h];
        const int c0 = I[I_LW0 + w], c1 = I[I_LW1 + w];
        const float fT = F[F_FT + t], fH = F[F_FH + h], fW = F[F_FW + w];
        #pragma unroll
        for (int jj = 0; jj < 3; ++jj) {
            const float* Sj = F + F_SC + jj * NIN;
            const int i0 = a0 * (HI * WI), i1 = a1 * (HI * WI);
            const float v000 = Sj[i0 + bh0 * WI + c0], v001 = Sj[i0 + bh0 * WI + c1];
            const float v010 = Sj[i0 + bh1 * WI + c0], v011 = Sj[i0 + bh1 * WI + c1];
            const float v100 = Sj[i1 + bh0 * WI + c0], v101 = Sj[i1 + bh0 * WI + c1];
            const float v110 = Sj[i1 + bh1 * WI + c0], v111 = Sj[i1 + bh1 * WI + c1];
            const float u00 = v000 * (1.f - fT) + v100 * fT;
            const float u01 = v001 * (1.f - fT) + v101 * fT;
            const float u10 = v010 * (1.f - fT) + v110 * fT;
            const float u11 = v011 * (1.f - fT) + v111 * fT;
            const float q0 = u00 * (1.f - fH) + u10 * fH;
            const float q1 = u01 * (1.f - fH) + u11 * fH;
            sh_g[jj][p] = q0 * (1.f - fW) + q1 * fW;
        }
    }
    __syncthreads();

    // ---- stage 2: z[p][o] = b1eff + Acoef·dv + sum_k wk * P[k][ipos][o] ----
    // thread = (og, pg): 4 consecutive channels o4=og*4, 8 positions p=pg*8+pp
    {
        const int og = tid & 63, pg = tid >> 6;
        const int o4 = og * 4;
        const float4 bz = *(const float4*)&F[F_B1 + o4];
        float4 Ac[6];
        #pragma unroll
        for (int i = 0; i < 6; ++i) Ac[i] = *(const float4*)&F[F_ACO + i * 256 + o4];
        for (int pp = 0; pp < 8; ++pp) {
            const int p = pg * 8 + pp;
            float a0 = bz.x, a1 = bz.y, a2 = bz.z, a3 = bz.w;
            #pragma unroll
            for (int i = 0; i < 6; ++i) {
                const float dv = sh_dv[p][i];
                a0 += Ac[i].x * dv; a1 += Ac[i].y * dv;
                a2 += Ac[i].z * dv; a3 += Ac[i].w * dv;
            }
            #pragma unroll
            for (int k = 0; k < 8; ++k) {
                const float wk = sh_wk[p][k];
                const ushort4x u = *(const ushort4x*)(P + ((size_t)(k * NIN + sh_ipos[p][k]) * 256 + o4));
                a0 += wk * bu2f(u.x); a1 += wk * bu2f(u.y);
                a2 += wk * bu2f(u.z); a3 += wk * bu2f(u.w);
            }
            short4x zz = { bbits(a0), bbits(a1), bbits(a2), bbits(a3) };
            *(short4x*)&zsh[p * ZPAD + o4] = zz;
        }
    }
    __syncthreads();

    // ---- stage 3: fc1 via MFMA (2 M-tiles) + gelu + fc2 partials in-register ----
    {
        const int wl = tid & 63, w = tid >> 6;
        const int col = wl & 15, quad = wl >> 4;
        f32x4 acc0[4] = { {0,0,0,0}, {0,0,0,0}, {0,0,0,0}, {0,0,0,0} };
        f32x4 acc1[4] = { {0,0,0,0}, {0,0,0,0}, {0,0,0,0}, {0,0,0,0} };
        const short8x* bp = (const short8x*)fc1P;
        #pragma unroll
        for (int kc = 0; kc < 8; ++kc) {
            const short8x a0 = *(const short8x*)&zsh[col * ZPAD + kc * 32 + quad * 8];
            const short8x a1 = *(const short8x*)&zsh[(col + 16) * ZPAD + kc * 32 + quad * 8];
            #pragma unroll
            for (int nt = 0; nt < 4; ++nt) {
                const short8x b = bp[(kc * 16 + w * 4 + nt) * 64 + wl];
                acc0[nt] = __builtin_amdgcn_mfma_f32_16x16x32_bf16(a0, b, acc0[nt], 0, 0, 0);
                acc1[nt] = __builtin_amdgcn_mfma_f32_16x16x32_bf16(a1, b, acc1[nt], 0, 0, 0);
            }
        }
        // gelu + fc2 partial sums; D layout: m = quad*4+r, n = w*64+nt*16+col
        float part[2][3][4];
        #pragma unroll
        for (int mt = 0; mt < 2; ++mt)
            #pragma unroll
            for (int jj = 0; jj < 3; ++jj)
                #pragma unroll
                for (int r = 0; r < 4; ++r) part[mt][jj][r] = 0.f;
        #pragma unroll
        for (int nt = 0; nt < 4; ++nt) {
            const int j = w * 64 + nt * 16 + col;
            const float fb = F[F_FC1B + j];
            const float w0 = F[F_FC2W + j];
            const float w1 = F[F_FC2W + 256 + j];
            const float w2 = F[F_FC2W + 512 + j];
            #pragma unroll
            for (int r = 0; r < 4; ++r) {
                float x = acc0[nt][r] + fb;
                float hh = 0.5f * x * (1.0f + erff(x * 0.70710678118654752f));
                part[0][0][r] += w0 * hh; part[0][1][r] += w1 * hh; part[0][2][r] += w2 * hh;
                x = acc1[nt][r] + fb;
                hh = 0.5f * x * (1.0f + erff(x * 0.70710678118654752f));
                part[1][0][r] += w0 * hh; part[1][1][r] += w1 * hh; part[1][2][r] += w2 * hh;
            }
        }
        // butterfly-reduce over the 16 col-lanes
        #pragma unroll
        for (int m = 1; m <= 8; m <<= 1)
            #pragma unroll
            for (int mt = 0; mt < 2; ++mt)
                #pragma unroll
                for (int jj = 0; jj < 3; ++jj)
                    #pragma unroll
                    for (int r = 0; r < 4; ++r)
                        part[mt][jj][r] += __shfl_xor(part[mt][jj][r], m, 64);
        if (col == 0) {
            #pragma unroll
            for (int mt = 0; mt < 2; ++mt)
                #pragma unroll
                for (int jj = 0; jj < 3; ++jj)
                    #pragma unroll
                    for (int r = 0; r < 4; ++r) {
                        const int p = mt * 16 + quad * 4 + r;
                        redc[(p * 4 + w) * 3 + jj] = part[mt][jj][r];
                    }
        }
    }
    __syncthreads();

    // ---- stage 4: combine 4 wave-partials + shortcut + store ----
    if (tid < 96) {
        const int p = tid / 3, jj = tid - 3 * p;
        float a = F[F_FC2B + jj] + sh_g[jj][p];
        #pragma unroll
        for (int w = 0; w < 4; ++w) a += redc[(p * 4 + w) * 3 + jj];
        const int oidx = jj * NOUT + pos0 + p;
        if (f32) ((float*)outv)[oidx] = a;
        else     ((bf16*)outv)[oidx] = f2b(a);
    }
}

extern "C" void kernel_launch(void* const* d_in, const int* in_sizes, int n_in,
                              void* d_out, int out_size, void* d_ws, size_t ws_size,
                              hipStream_t stream) {
    const void* feat    = d_in[0];
    const void* dw1_w   = d_in[1];
    const void* dw1_b   = d_in[2];
    const void* pw1_w   = d_in[3];
    const void* pw1_b   = d_in[4];
    const void* fc1_w   = d_in[5];
    const void* fc1_b   = d_in[6];
    const void* fc2_w   = d_in[7];
    const void* fc2_b   = d_in[8];
    const void* sc_dw_w = d_in[9];
    const void* sc_dw_b = d_in[10];
    const void* sc_pw_w = d_in[11];
    const void* sc_pw_b = d_in[12];

    const size_t P_BYTES = (size_t)8 * NIN * 256 * 2;   // 39,321,600
    const size_t FC1P_BYTES = (size_t)256 * 256 * 2;    // 131,072
    bf16*  P    = (bf16*)d_ws;
    bf16*  fc1P = (bf16*)((char*)d_ws + P_BYTES);
    float* F    = (float*)((char*)d_ws + P_BYTES + FC1P_BYTES);
    int*   I    = (int*)(F + F_END);
    // total ws need ~40.2 MB

    k_setup<<<288, 256, 0, stream>>>(feat, dw1_w, dw1_b, pw1_w, pw1_b, fc1_w, fc1_b,
                                     fc2_w, fc2_b, sc_dw_w, sc_dw_b, sc_pw_w, sc_pw_b,
                                     fc1P, F, I);
    k_corner<<<NIN / 16, 256, 0, stream>>>(feat, F, I, P);
    k_main<<<NOUT / MPOS, 256, 0, stream>>>(P, fc1P, F, I, (void*)d_out);
}

// Round 6
// 171.728 us; speedup vs baseline: 3.5427x; 1.2292x over previous
//
#include <hip/hip_runtime.h>
#include <hip/hip_bf16.h>

using bf16 = __hip_bfloat16;
typedef __attribute__((ext_vector_type(8))) short short8x;            // 8 bf16 (4 VGPRs)
typedef __attribute__((ext_vector_type(4))) short short4x;            // 4 bf16
typedef __attribute__((ext_vector_type(4))) unsigned short ushort4x;  // 4 bf16 bits
typedef __attribute__((ext_vector_type(4))) float f32x4;              // MFMA accumulator

__device__ __forceinline__ float b2f(bf16 x) { return __bfloat162float(x); }
__device__ __forceinline__ bf16  f2b(float x) { return __float2bfloat16(x); }
__device__ __forceinline__ short bbits(float x) { bf16 b = f2b(x); short s; __builtin_memcpy(&s, &b, 2); return s; }
__device__ __forceinline__ float bu2f(unsigned short s) {
    unsigned v = ((unsigned)s) << 16; float f; __builtin_memcpy(&f, &v, 4); return f;
}
// flag-dispatched input load: f32==1 -> fp32 storage, else bf16 storage
__device__ __forceinline__ float ldin(const void* p, int i, int f32) {
    return f32 ? ((const float*)p)[i] : b2f(((const bf16*)p)[i]);
}

// problem dims (fixed by setup_inputs)
#define TI 6
#define HI 40
#define WI 40
#define TO 12
#define HO 80
#define WO 80
#define NIN (TI*HI*WI)    // 9600
#define NOUT (TO*HO*WO)   // 76800

// ---------------- workspace layout ----------------
// [0, P_BYTES)            : P bf16 [8][NIN][256]  (corner projections)
// [+FC1P_BYTES)           : fc1P bf16 [8 kc][16 nt][64 lane][8]  (fc1 B-fragments)
// [+W1FP_BYTES)           : W1fP bf16 [8 k][2 kc][16 nt][64 lane][8]  (W1f B-fragments)
// float region F (offsets in floats):
#define F_B1    0                       // [256] effective bias
#define F_ACO   (F_B1 + 256)            // [6][256] rel-coord coefficients
#define F_SCW   (F_ACO + 6*256)         // [3][64] sc_pw_w*sc_dw_w
#define F_SCB   (F_SCW + 3*64)          // [3] folded sc bias (pad 4)
#define F_SC    (F_SCB + 4)             // [3][NIN] shortcut conv output
#define F_DT    (F_SC + 3*NIN)          // [2][TO] signed d (t axis)
#define F_DH    (F_DT + 2*TO)           // [2][HO]
#define F_DW    (F_DH + 2*HO)           // [2][WO]
#define F_FT    (F_DW + 2*WO)           // [TO] trilinear frac
#define F_FH    (F_FT + TO)             // [HO]
#define F_FW    (F_FH + HO)             // [WO]
#define F_FC1B  (F_FW + WO)             // [256] fc1 bias (fp32 staged)
#define F_FC2W  (F_FC1B + 256)          // [3*256] fc2 weights (fp32 staged)
#define F_FC2B  (F_FC2W + 768)          // [3] fc2 bias (pad 4)
#define F_END   (F_FC2B + 4)
// int region I (offsets in ints), starts right after F region:
#define I_IT    0                       // [2][TO] nearest idx
#define I_IH    (I_IT + 2*TO)           // [2][HO]
#define I_IW    (I_IH + 2*HO)           // [2][WO]
#define I_LT0   (I_IW + 2*WO)           // [TO] trilinear i0
#define I_LT1   (I_LT0 + TO)
#define I_LH0   (I_LT1 + TO)
#define I_LH1   (I_LH0 + HO)
#define I_LW0   (I_LH1 + HO)
#define I_LW1   (I_LW0 + WO)
#define I_FLAG  (I_LW1 + WO)            // [1] 1 = fp32 storage, 0 = bf16 storage
#define I_END   (I_FLAG + 1)

#define MPOS 32     // positions per k_main block
#define ZPAD 264    // bf16 row stride for z LDS tile
#define FT_S 72     // bf16 row stride for feat tile in k_corner (16B-aligned rows)

// per-axis tables, replicating reference `near` (eps=1e-6, round-half-even) and `lin_idx`
__device__ __forceinline__ void axis_tables(int i, int n_out, int n_in,
                                            float* dvals, int* ivals,
                                            int* l0, int* l1, float* fr) {
    const float r_out = 1.0f / (float)n_out;
    const float r_in  = 1.0f / (float)n_in;
    const float c = -1.0f + r_out + 2.0f * r_out * (float)i;
    #pragma unroll
    for (int v = 0; v < 2; ++v) {
        const float vv = v ? 1.0f : -1.0f;
        float cc = c + vv * r_in + 1e-6f;
        cc = fminf(fmaxf(cc, -1.0f + 1e-6f), 1.0f - 1e-6f);
        float fx = rintf(((cc + 1.0f) * (float)n_in - 1.0f) * 0.5f);
        fx = fminf(fmaxf(fx, 0.0f), (float)(n_in - 1));
        const int idx = (int)fx;
        const float l = -1.0f + r_in + 2.0f * r_in * (float)idx;
        dvals[v * n_out + i] = (c - l) * (float)n_in;
        ivals[v * n_out + i] = idx;
    }
    float x = fminf(fmaxf(((c + 1.0f) * (float)n_in - 1.0f) * 0.5f, 0.0f), (float)(n_in - 1));
    const float x0 = floorf(x);
    fr[i] = x - x0;
    const int i0 = (int)x0;
    l0[i] = i0;
    l1[i] = min(i0 + 1, n_in - 1);
}

// ---------------- kernel A: merged setup (352 blocks) ----------------
// blocks 0..255 : B1/ACO fold per output channel o (block 0 also: tables + small folds)
// blocks 256..287: pack fc1 -> fc1P B-fragments
// blocks 288..351: pack pw1_w*dw1_w (feature cols) -> W1fP B-fragments
__global__ __launch_bounds__(256)
void k_setup(const void* __restrict__ feat,
             const void* __restrict__ dw1_w, const void* __restrict__ dw1_b,
             const void* __restrict__ pw1_w, const void* __restrict__ pw1_b,
             const void* __restrict__ fc1_w, const void* __restrict__ fc1_b,
             const void* __restrict__ fc2_w, const void* __restrict__ fc2_b,
             const void* __restrict__ sc_dw_w, const void* __restrict__ sc_dw_b,
             const void* __restrict__ sc_pw_w, const void* __restrict__ sc_pw_b,
             bf16* __restrict__ fc1P, bf16* __restrict__ W1fP,
             float* __restrict__ F, int* __restrict__ I) {
    const int tid = threadIdx.x;
    const int b = blockIdx.x;
    __shared__ int sflag;
    // per-block dtype detection (wave-0 ballot): even halfwords of fp32 data
    // are mantissa junk (~15% in bf16-exponent window); of bf16 data ~100%.
    if (tid < 64) {
        const unsigned short* u = (const unsigned short*)feat;
        const unsigned e = (u[2 * tid] >> 7) & 0xFFu;
        const unsigned long long m = __ballot(e >= 0x68u && e <= 0x8Eu);
        if (tid == 0) sflag = (__popcll(m) < 32) ? 1 : 0;
    }
    __syncthreads();
    const int f32 = sflag;

    if (b >= 288) {           // ---- W1f pack duty ----
        const int g = (b - 288) * 256 + tid;     // 0..16383
        const int k = g >> 11, kc = (g >> 10) & 1, nt = (g >> 6) & 15, wl = g & 63;
        const int n = nt * 16 + (wl & 15);
        const int k0 = kc * 32 + (wl >> 4) * 8;
        bf16 v[8];
        #pragma unroll
        for (int jj = 0; jj < 8; ++jj) {
            const int ch = 24 + k * 64 + k0 + jj;
            v[jj] = f2b(ldin(pw1_w, n * 539 + ch, f32) * ldin(dw1_w, ch, f32));
        }
        *(short8x*)&W1fP[(size_t)g * 8] = *(short8x*)v;
        return;
    }
    if (b >= 256) {           // ---- fc1 pack duty ----
        const int g = (b - 256) * 256 + tid;     // 0..8191
        const int kc = g >> 10, nt = (g >> 6) & 15, wl = g & 63;
        const int n = nt * 16 + (wl & 15);
        const int k0 = kc * 32 + (wl >> 4) * 8;
        bf16 v[8];
        #pragma unroll
        for (int jj = 0; jj < 8; ++jj) v[jj] = f2b(ldin(fc1_w, n * 256 + k0 + jj, f32));
        *(short8x*)&fc1P[(size_t)g * 8] = *(short8x*)v;
        return;
    }

    // ---- fold duty: B1 + ACO for output channel o = b ----
    __shared__ float row[539];
    __shared__ float red[256];
    const int o = b;

    for (int ch = tid; ch < 539; ch += 256) row[ch] = ldin(pw1_w, o * 539 + ch, f32);
    __syncthreads();

    float s = 0.f;
    for (int ch = tid; ch < 539; ch += 256) s += row[ch] * ldin(dw1_b, ch, f32);
    red[tid] = s;
    __syncthreads();
    for (int st = 128; st > 0; st >>= 1) {
        if (tid < st) red[tid] += red[tid + st];
        __syncthreads();
    }

    if (tid == 0) {
        float bacc = ldin(pw1_b, o, f32) + red[0];
        #pragma unroll
        for (int ch = 536; ch < 539; ++ch)
            bacc += 2.0f * row[ch] * ldin(dw1_w, ch, f32);
        F[F_B1 + o] = bacc;

        float A[6] = {0.f, 0.f, 0.f, 0.f, 0.f, 0.f};
        #pragma unroll
        for (int k = 0; k < 8; ++k) {
            A[(k >> 2)]           += row[3*k + 0] * ldin(dw1_w, 3*k + 0, f32);
            A[2 + ((k >> 1) & 1)] += row[3*k + 1] * ldin(dw1_w, 3*k + 1, f32);
            A[4 + (k & 1)]        += row[3*k + 2] * ldin(dw1_w, 3*k + 2, f32);
        }
        #pragma unroll
        for (int i = 0; i < 6; ++i) F[F_ACO + i * 256 + o] = A[i];
    }

    if (b == 0) {             // ---- prep0 duty (runs alongside fold in block 0) ----
        if (tid == 0) I[I_FLAG] = f32;
        F[F_FC1B + tid] = ldin(fc1_b, tid, f32);
        for (int r = tid; r < 768; r += 256) F[F_FC2W + r] = ldin(fc2_w, r, f32);
        if (tid < 3) F[F_FC2B + tid] = ldin(fc2_b, tid, f32);
        if (tid < 3) {
            const int j = tid;
            float sb = ldin(sc_pw_b, j, f32);
            for (int c = 0; c < 64; ++c) {
                const float pw = ldin(sc_pw_w, j * 64 + c, f32);
                F[F_SCW + j * 64 + c] = pw * ldin(sc_dw_w, c, f32);
                sb += pw * ldin(sc_dw_b, c, f32);
            }
            F[F_SCB + j] = sb;
        }
        if (tid < TO) axis_tables(tid, TO, TI, F + F_DT, I + I_IT, I + I_LT0, I + I_LT1, F + F_FT);
        if (tid < HO) axis_tables(tid, HO, HI, F + F_DH, I + I_IH, I + I_LH0, I + I_LH1, F + F_FH);
        if (tid < WO) axis_tables(tid, WO, WI, F + F_DW, I + I_IW, I + I_LW0, I + I_LW1, F + F_FW);
    }
}

// ---------------- kernel B: MFMA corner projections P + shortcut sc ----------------
// grid (300 pos-tiles, 8 corners). Per block: M=32 positions, N=256, K=64.
__global__ __launch_bounds__(256)
void k_corner(const void* __restrict__ feat, float* __restrict__ F,
              const int* __restrict__ I, const bf16* __restrict__ W1fP,
              bf16* __restrict__ P) {
    const int tid = threadIdx.x;
    const int pt = blockIdx.x, k = blockIdx.y;
    const int pos0 = pt * 32;
    const int f32 = I[I_FLAG];

    __shared__ __align__(16) short ft[32 * FT_S];   // feat tile transposed [p][c] bf16
    __shared__ __align__(16) short zt[32 * ZPAD];   // P tile [p][o] bf16

    // stage feat tile (transpose [c][pos] -> [p][c]); bf16 conversion lossless
    {
        const int p = tid & 31, c0 = tid >> 5;   // c0 in 0..7
        #pragma unroll
        for (int cc = 0; cc < 8; ++cc) {
            const int c = c0 * 8 + cc;
            ft[p * FT_S + c] = bbits(ldin(feat, c * NIN + pos0 + p, f32));
        }
    }
    __syncthreads();

    // MFMA: 2 M-tiles x 4 N-tiles x 2 K-chunks per wave
    const int wl = tid & 63, w = tid >> 6;
    const int col = wl & 15, quad = wl >> 4;
    f32x4 acc[2][4] = { { {0,0,0,0},{0,0,0,0},{0,0,0,0},{0,0,0,0} },
                        { {0,0,0,0},{0,0,0,0},{0,0,0,0},{0,0,0,0} } };
    const short8x* bp = (const short8x*)W1fP;
    #pragma unroll
    for (int kc = 0; kc < 2; ++kc) {
        const short8x a0 = *(const short8x*)&ft[col * FT_S + kc * 32 + quad * 8];
        const short8x a1 = *(const short8x*)&ft[(col + 16) * FT_S + kc * 32 + quad * 8];
        #pragma unroll
        for (int nt = 0; nt < 4; ++nt) {
            const short8x bb = bp[((k * 2 + kc) * 16 + (w * 4 + nt)) * 64 + wl];
            acc[0][nt] = __builtin_amdgcn_mfma_f32_16x16x32_bf16(a0, bb, acc[0][nt], 0, 0, 0);
            acc[1][nt] = __builtin_amdgcn_mfma_f32_16x16x32_bf16(a1, bb, acc[1][nt], 0, 0, 0);
        }
    }

    // shortcut (only corner-0 blocks): sc[j][pos] from the staged tile
    if (k == 0 && tid < 96) {
        const int j = tid >> 5, p = tid & 31;
        float s = F[F_SCB + j];
        for (int c = 0; c < 64; ++c)
            s += bu2f((unsigned short)ft[p * FT_S + c]) * F[F_SCW + j * 64 + c];
        F[F_SC + j * NIN + pos0 + p] = s;
    }

    // write accumulators to LDS tile (D layout: m=quad*4+r, n=w*64+nt*16+col)
    #pragma unroll
    for (int mt = 0; mt < 2; ++mt)
        #pragma unroll
        for (int nt = 0; nt < 4; ++nt) {
            const int n = w * 64 + nt * 16 + col;
            #pragma unroll
            for (int r = 0; r < 4; ++r)
                zt[(mt * 16 + quad * 4 + r) * ZPAD + n] = bbits(acc[mt][nt][r]);
        }
    __syncthreads();

    // coalesced store: 32 rows x 512B contiguous per row
    #pragma unroll
    for (int q = 0; q < 4; ++q) {
        const int i = q * 256 + tid;            // 0..1023 chunks of 8 bf16
        const int p = i >> 5, c8 = i & 31;
        const short8x v = *(const short8x*)&zt[p * ZPAD + c8 * 8];
        *(short8x*)(P + ((size_t)(k * NIN + pos0 + p)) * 256 + c8 * 8) = v;
    }
}

// ---------------- kernel C: main fused MLP (MFMA fc1, in-register fc2) ----------------
__global__ __launch_bounds__(256, 4)
void k_main(const bf16* __restrict__ P, const bf16* __restrict__ fc1P,
            const float* __restrict__ F, const int* __restrict__ I,
            void* __restrict__ outv) {
    const int tid = threadIdx.x;
    const int pos0 = blockIdx.x * MPOS;
    const int f32 = I[I_FLAG];

    __shared__ __align__(16) short zsh[MPOS * ZPAD];  // z bf16, [p][o]
    __shared__ float redc[MPOS * 4 * 3];              // fc2 per-wave partials [p][w][jj]
    __shared__ int   sh_ipos[MPOS][8];
    __shared__ float sh_wk[MPOS][8];
    __shared__ float sh_dv[MPOS][6];
    __shared__ float sh_g[3][MPOS];

    // ---- stage 1: per-position scalars (threads 0..31) ----
    if (tid < MPOS) {
        const int p = tid;
        const int pos = pos0 + p;
        const int t = pos / (HO * WO);
        const int rem = pos - t * (HO * WO);
        const int h = rem / WO;
        const int w = rem - h * WO;
        const int   iTa[2] = { I[I_IT + t], I[I_IT + TO + t] };
        const float dTv[2] = { F[F_DT + t], F[F_DT + TO + t] };
        const int   iHa[2] = { I[I_IH + h], I[I_IH + HO + h] };
        const float dHv[2] = { F[F_DH + h], F[F_DH + HO + h] };
        const int   iWa[2] = { I[I_IW + w], I[I_IW + WO + w] };
        const float dWv[2] = { F[F_DW + w], F[F_DW + WO + w] };
        sh_dv[p][0] = dTv[0]; sh_dv[p][1] = dTv[1];
        sh_dv[p][2] = dHv[0]; sh_dv[p][3] = dHv[1];
        sh_dv[p][4] = dWv[0]; sh_dv[p][5] = dWv[1];
        const float aT[2] = { fabsf(dTv[0]), fabsf(dTv[1]) };
        const float aH[2] = { fabsf(dHv[0]), fabsf(dHv[1]) };
        const float aW[2] = { fabsf(dWv[0]), fabsf(dWv[1]) };
        const float tot = (aT[0] + aT[1]) * (aH[0] + aH[1]) * (aW[0] + aW[1]) + 8e-9f;
        #pragma unroll
        for (int k = 0; k < 8; ++k) {
            const int at = k >> 2, ah = (k >> 1) & 1, aw = k & 1;
            sh_wk[p][k] = (aT[1 - at] * aH[1 - ah] * aW[1 - aw] + 1e-9f) / tot;
            sh_ipos[p][k] = iTa[at] * (HI * WI) + iHa[ah] * WI + iWa[aw];
        }
        // trilinear shortcut g
        const int a0 = I[I_LT0 + t], a1 = I[I_LT1 + t];
        const int bh0 = I[I_LH0 + h], bh1 = I[I_LH1 + h];
        const int c0 = I[I_LW0 + w], c1 = I[I_LW1 + w];
        const float fT = F[F_FT + t], fH = F[F_FH + h], fW = F[F_FW + w];
        #pragma unroll
        for (int jj = 0; jj < 3; ++jj) {
            const float* Sj = F + F_SC + jj * NIN;
            const int i0 = a0 * (HI * WI), i1 = a1 * (HI * WI);
            const float v000 = Sj[i0 + bh0 * WI + c0], v001 = Sj[i0 + bh0 * WI + c1];
            const float v010 = Sj[i0 + bh1 * WI + c0], v011 = Sj[i0 + bh1 * WI + c1];
            const float v100 = Sj[i1 + bh0 * WI + c0], v101 = Sj[i1 + bh0 * WI + c1];
            const float v110 = Sj[i1 + bh1 * WI + c0], v111 = Sj[i1 + bh1 * WI + c1];
            const float u00 = v000 * (1.f - fT) + v100 * fT;
            const float u01 = v001 * (1.f - fT) + v101 * fT;
            const float u10 = v010 * (1.f - fT) + v110 * fT;
            const float u11 = v011 * (1.f - fT) + v111 * fT;
            const float q0 = u00 * (1.f - fH) + u10 * fH;
            const float q1 = u01 * (1.f - fH) + u11 * fH;
            sh_g[jj][p] = q0 * (1.f - fW) + q1 * fW;
        }
    }
    __syncthreads();

    // ---- stage 2: z[p][o] = b1eff + Acoef·dv + sum_k wk * P[k][ipos][o] ----
    // thread = (og, pg): 4 consecutive channels o4=og*4, 8 positions p=pg*8+pp
    {
        const int og = tid & 63, pg = tid >> 6;
        const int o4 = og * 4;
        const float4 bz = *(const float4*)&F[F_B1 + o4];
        float4 Ac[6];
        #pragma unroll
        for (int i = 0; i < 6; ++i) Ac[i] = *(const float4*)&F[F_ACO + i * 256 + o4];
        for (int pp = 0; pp < 8; ++pp) {
            const int p = pg * 8 + pp;
            float a0 = bz.x, a1 = bz.y, a2 = bz.z, a3 = bz.w;
            #pragma unroll
            for (int i = 0; i < 6; ++i) {
                const float dv = sh_dv[p][i];
                a0 += Ac[i].x * dv; a1 += Ac[i].y * dv;
                a2 += Ac[i].z * dv; a3 += Ac[i].w * dv;
            }
            #pragma unroll
            for (int k = 0; k < 8; ++k) {
                const float wk = sh_wk[p][k];
                const ushort4x u = *(const ushort4x*)(P + ((size_t)(k * NIN + sh_ipos[p][k]) * 256 + o4));
                a0 += wk * bu2f(u.x); a1 += wk * bu2f(u.y);
                a2 += wk * bu2f(u.z); a3 += wk * bu2f(u.w);
            }
            short4x zz = { bbits(a0), bbits(a1), bbits(a2), bbits(a3) };
            *(short4x*)&zsh[p * ZPAD + o4] = zz;
        }
    }
    __syncthreads();

    // ---- stage 3: fc1 via MFMA (2 M-tiles) + gelu + fc2 partials in-register ----
    {
        const int wl = tid & 63, w = tid >> 6;
        const int col = wl & 15, quad = wl >> 4;
        f32x4 acc0[4] = { {0,0,0,0}, {0,0,0,0}, {0,0,0,0}, {0,0,0,0} };
        f32x4 acc1[4] = { {0,0,0,0}, {0,0,0,0}, {0,0,0,0}, {0,0,0,0} };
        const short8x* bp = (const short8x*)fc1P;
        #pragma unroll
        for (int kc = 0; kc < 8; ++kc) {
            const short8x a0 = *(const short8x*)&zsh[col * ZPAD + kc * 32 + quad * 8];
            const short8x a1 = *(const short8x*)&zsh[(col + 16) * ZPAD + kc * 32 + quad * 8];
            #pragma unroll
            for (int nt = 0; nt < 4; ++nt) {
                const short8x b = bp[(kc * 16 + w * 4 + nt) * 64 + wl];
                acc0[nt] = __builtin_amdgcn_mfma_f32_16x16x32_bf16(a0, b, acc0[nt], 0, 0, 0);
                acc1[nt] = __builtin_amdgcn_mfma_f32_16x16x32_bf16(a1, b, acc1[nt], 0, 0, 0);
            }
        }
        // gelu + fc2 partial sums; D layout: m = quad*4+r, n = w*64+nt*16+col
        float part[2][3][4];
        #pragma unroll
        for (int mt = 0; mt < 2; ++mt)
            #pragma unroll
            for (int jj = 0; jj < 3; ++jj)
                #pragma unroll
                for (int r = 0; r < 4; ++r) part[mt][jj][r] = 0.f;
        #pragma unroll
        for (int nt = 0; nt < 4; ++nt) {
            const int j = w * 64 + nt * 16 + col;
            const float fb = F[F_FC1B + j];
            const float w0 = F[F_FC2W + j];
            const float w1 = F[F_FC2W + 256 + j];
            const float w2 = F[F_FC2W + 512 + j];
            #pragma unroll
            for (int r = 0; r < 4; ++r) {
                float x = acc0[nt][r] + fb;
                float hh = 0.5f * x * (1.0f + erff(x * 0.70710678118654752f));
                part[0][0][r] += w0 * hh; part[0][1][r] += w1 * hh; part[0][2][r] += w2 * hh;
                x = acc1[nt][r] + fb;
                hh = 0.5f * x * (1.0f + erff(x * 0.70710678118654752f));
                part[1][0][r] += w0 * hh; part[1][1][r] += w1 * hh; part[1][2][r] += w2 * hh;
            }
        }
        // butterfly-reduce over the 16 col-lanes
        #pragma unroll
        for (int m = 1; m <= 8; m <<= 1)
            #pragma unroll
            for (int mt = 0; mt < 2; ++mt)
                #pragma unroll
                for (int jj = 0; jj < 3; ++jj)
                    #pragma unroll
                    for (int r = 0; r < 4; ++r)
                        part[mt][jj][r] += __shfl_xor(part[mt][jj][r], m, 64);
        if (col == 0) {
            #pragma unroll
            for (int mt = 0; mt < 2; ++mt)
                #pragma unroll
                for (int jj = 0; jj < 3; ++jj)
                    #pragma unroll
                    for (int r = 0; r < 4; ++r) {
                        const int p = mt * 16 + quad * 4 + r;
                        redc[(p * 4 + w) * 3 + jj] = part[mt][jj][r];
                    }
        }
    }
    __syncthreads();

    // ---- stage 4: combine 4 wave-partials + shortcut + store ----
    if (tid < 96) {
        const int p = tid / 3, jj = tid - 3 * p;
        float a = F[F_FC2B + jj] + sh_g[jj][p];
        #pragma unroll
        for (int w = 0; w < 4; ++w) a += redc[(p * 4 + w) * 3 + jj];
        const int oidx = jj * NOUT + pos0 + p;
        if (f32) ((float*)outv)[oidx] = a;
        else     ((bf16*)outv)[oidx] = f2b(a);
    }
}

extern "C" void kernel_launch(void* const* d_in, const int* in_sizes, int n_in,
                              void* d_out, int out_size, void* d_ws, size_t ws_size,
                              hipStream_t stream) {
    const void* feat    = d_in[0];
    const void* dw1_w   = d_in[1];
    const void* dw1_b   = d_in[2];
    const void* pw1_w   = d_in[3];
    const void* pw1_b   = d_in[4];
    const void* fc1_w   = d_in[5];
    const void* fc1_b   = d_in[6];
    const void* fc2_w   = d_in[7];
    const void* fc2_b   = d_in[8];
    const void* sc_dw_w = d_in[9];
    const void* sc_dw_b = d_in[10];
    const void* sc_pw_w = d_in[11];
    const void* sc_pw_b = d_in[12];

    const size_t P_BYTES    = (size_t)8 * NIN * 256 * 2;   // 39,321,600
    const size_t FC1P_BYTES = (size_t)256 * 256 * 2;       // 131,072
    const size_t W1FP_BYTES = (size_t)8 * 64 * 256 * 2;    // 262,144
    bf16*  P    = (bf16*)d_ws;
    bf16*  fc1P = (bf16*)((char*)d_ws + P_BYTES);
    bf16*  W1fP = (bf16*)((char*)d_ws + P_BYTES + FC1P_BYTES);
    float* F    = (float*)((char*)d_ws + P_BYTES + FC1P_BYTES + W1FP_BYTES);
    int*   I    = (int*)(F + F_END);
    // total ws need ~39.9 MB

    k_setup<<<352, 256, 0, stream>>>(feat, dw1_w, dw1_b, pw1_w, pw1_b, fc1_w, fc1_b,
                                     fc2_w, fc2_b, sc_dw_w, sc_dw_b, sc_pw_w, sc_pw_b,
                                     fc1P, W1fP, F, I);
    k_corner<<<dim3(NIN / 32, 8), 256, 0, stream>>>(feat, F, I, W1fP, P);
    k_main<<<NOUT / MPOS, 256, 0, stream>>>(P, fc1P, F, I, (void*)d_out);
}